// Round 9
// baseline (439.356 us; speedup 1.0000x reference)
//
#include <hip/hip_runtime.h>
#include <hip/hip_fp16.h>
#include <stdint.h>

#define N_NODES 50000
#define N_EDGES 800000

typedef unsigned short u16;
typedef unsigned int u32;
typedef __attribute__((ext_vector_type(8))) short short8;   // 8 bf16 = A/B frag
typedef __attribute__((ext_vector_type(4))) float f32x4;    // C/D frag
typedef __attribute__((ext_vector_type(4))) u32 u32x4;
typedef __attribute__((ext_vector_type(2))) u32 u32x2;

// wave-private LDS exchange: DS ops in-order per wave; only lgkmcnt drain needed.
#define WAVE_SYNC() asm volatile("s_waitcnt lgkmcnt(0)" ::: "memory")

// ---------------- helpers ----------------
__device__ __forceinline__ float b2f(u16 v) {
    u32 u = ((u32)v) << 16; float f; __builtin_memcpy(&f, &u, 4); return f;
}
__device__ __forceinline__ u16 f2b(float f) {
    u32 u; __builtin_memcpy(&u, &f, 4);
    return (u16)((u + 0x8000u) >> 16);
}
__device__ __forceinline__ float lo2f(u32 p) {
    u32 u = p << 16; float f; __builtin_memcpy(&f, &u, 4); return f;
}
__device__ __forceinline__ float hi2f(u32 p) {
    u32 u = p & 0xffff0000u; float f; __builtin_memcpy(&f, &u, 4); return f;
}
// pack two f32 -> two bf16 (round-half-up) in 3 ops via v_perm_b32
__device__ __forceinline__ u32 pack2(float a, float b) {
    u32 ua, ub; __builtin_memcpy(&ua, &a, 4); __builtin_memcpy(&ub, &b, 4);
    return __builtin_amdgcn_perm(ub + 0x8000u, ua + 0x8000u, 0x07060302u);
}
__device__ __forceinline__ f32x4 mfma16(short8 a, short8 b, f32x4 c) {
    return __builtin_amdgcn_mfma_f32_16x16x32_bf16(a, b, c, 0, 0, 0);
}

// bf16-vs-f32 input detection, inlined per block (wave-uniform result).
__device__ __forceinline__ bool detect_bf(const void* nf) {
    u32 w = ((const u32*)nf)[threadIdx.x & 63];
    u32 lo = w & 0xffffu;
    int e = (int)((lo >> 7) & 0xff);
    int good = ((e >= 118 && e <= 132) || lo == 0) ? 1 : 0;
    unsigned long long b = __ballot(good != 0);
    return __popcll(b) >= 48;
}

// ---- LUT tanh: 256 segments (f16 intercept/slope packed in u32), step 1/32
// over [0,8); y = fma(s, a, b), sign via v_bfi. err ~1e-3 (< bf16 storage noise).
#define TANH_TBL_N 256
__device__ __forceinline__ void load_tbl(const u32* __restrict__ g, u32* tbl) {
    int i = (int)threadIdx.x;
    if (i < TANH_TBL_N) tbl[i] = g[i];
    __syncthreads();
}
__device__ __forceinline__ float lut_tanh(const u32* __restrict__ tbl, float x) {
    float a = __builtin_fabsf(x);
    a = fminf(a, 7.96875f);
    int i = (int)(a * 32.f);
    u32 e = tbl[i];
    __half2 h2; __builtin_memcpy(&h2, &e, 4);
    float b = __half2float(__low2half(h2));
    float s = __half2float(__high2half(h2));
    return copysignf(fmaf(s, a, b), x);
}

// ---------------- f32 weight buffer offsets (biases/LN/head only) ----------------
enum : int {
    NE_B0 = 704,   NE_B1 = 4864,  NE_B2 = 9024,
    EE_B0 = 9280,  EE_B1 = 13440, EE_B2 = 17600,
    MP_B0 = 42240, LNW_O = 42624, LNB_O = 43008, MP_B1 = 67968,
    PI_B0 = 72256, PI_B1 = 76416, PI_W2 = 76480, PI_B2 = 76608,
    W_TOTAL = 76610
};

// fragment-buffer layer bases (frag id; 512 bf16 per frag)
enum : int {
    FR_EE1 = 0, FR_EE2 = 4, FR_EE3 = 12, FR_NE1 = 20, FR_NE2 = 24, FR_NE3 = 32,
    FR_MP0 = 40, FR_MP1 = 88, FR_PI0 = 136, FR_PI1 = 144, FR_TOTAL = 152
};

// ---------------- workspace layout (bytes) ----------------
#define OFF_W       ((size_t)0)
#define OFF_WB      ((size_t)0x61000)      // 152*512*2 = 155648 B
#define OFF_TBL     ((size_t)0x88000)      // 256 u32 = 1 KB
#define OFF_XB0     ((size_t)0x90000)      // 6.4 MB bf16
#define OFF_XB1     ((size_t)0x700000)     // 6.4 MB bf16
#define OFF_H64B    ((size_t)0xE00000)     // 6.4 MB bf16
#define OFF_E       ((size_t)0x1500000)    // ebuf: up to 850k x 64 bf16
#define OFF_ROWPTR  ((size_t)0x8300000)    // prow (padded CSR), N+1 ints
#define OFF_CURSOR  ((size_t)0x8340000)
#define OFF_CNT     ((size_t)0x8380000)
#define OFF_PERM    ((size_t)0x83C0000)
#define OFF_SRCS    ((size_t)0x8700000)    // padded srcs; pads written by scanC
#define OFF_BSUM    ((size_t)0x8A80000)

struct Ptrs24 { const void* p[24]; };
// 0 ne_w0 1 ne_b0 2 ne_w1 3 ne_b1 4 ne_w2 5 ne_b2 6 ee_w0 7 ee_b0 8 ee_w1 9 ee_b1
// 10 ee_w2 11 ee_b2 12 mp_w0 13 mp_b0 14 mp_ln_w 15 mp_ln_b 16 mp_w1 17 mp_b1
// 18 pi_w0 19 pi_b0 20 pi_w1 21 pi_b1 22 pi_w2 23 pi_b2

// ---------------- one-shot prep: frags + biases + LUT + cnts-zero ----------------
#define PREP_FRAG   (FR_TOTAL * 512)          // 77824
#define PREP_BIAS   (PREP_FRAG + 1986)        // 79810
#define PREP_LUT    (PREP_BIAS + TANH_TBL_N)  // 80066
#define PREP_TOTAL  (PREP_LUT + N_NODES)      // 130066

__global__ void prep_kernel(const void* nf, Ptrs24 ps, float* __restrict__ W,
                            u16* __restrict__ Wb, u32* __restrict__ gtbl,
                            int* __restrict__ cnts) {
    bool bf = detect_bf(nf);
    int t = blockIdx.x * blockDim.x + threadIdx.x;
    if (t < PREP_FRAG) {
        // bake bf16 MFMA A-frag directly from source weights (w[n][k] row-major)
        const int base[15] = {FR_EE1,FR_EE2,FR_EE3,FR_NE1,FR_NE2,FR_NE3,
                              FR_MP0,FR_MP0+16,FR_MP0+32, FR_MP1,FR_MP1+16,FR_MP1+32,
                              FR_PI0,FR_PI1,FR_TOTAL};
        const int psrc[14]  = {6,8,10, 0,2,4, 12,12,12, 16,16,16, 18,20};
        const int soff[14]  = {0,0,0, 0,0,0, 0,8192,16384, 0,8192,16384, 0,0};
        const int kreal[14] = {3,64,64, 11,64,64, 64,64,64, 128,128,128, 64,64};
        const int nn[14]    = {64,64,64, 64,64,64, 128,128,128, 64,64,64, 64,64};
        int f = t >> 9, r = t & 511, lane = r >> 3, j = r & 7;
        int l = 0;
        while (f >= base[l + 1]) l++;
        int lf = f - base[l];
        int NT = nn[l] >> 4;
        int kt = lf / NT, nt = lf % NT;
        int k = kt * 32 + (lane >> 4) * 8 + j;
        int n = nt * 16 + (lane & 15);
        float v = 0.f;
        if (k < kreal[l]) {
            long idx = (long)soff[l] + (long)n * kreal[l] + k;
            const void* p = ps.p[psrc[l]];
            v = bf ? b2f(((const u16*)p)[idx]) : ((const float*)p)[idx];
        }
        u32 u; __builtin_memcpy(&u, &v, 4);
        Wb[t] = (u16)((u + 0x7fffu + ((u >> 16) & 1u)) >> 16);   // RNE
        return;
    }
    if (t < PREP_BIAS) {
        int t2 = t - PREP_FRAG;
        const int cnt[14]  = {64,64,64, 64,64,64, 384,384,384,192, 64,64,128,2};
        const int wdst[14] = {NE_B0,NE_B1,NE_B2, EE_B0,EE_B1,EE_B2,
                              MP_B0,LNW_O,LNB_O,MP_B1, PI_B0,PI_B1,PI_W2,PI_B2};
        const int sp[14]   = {1,3,5, 7,9,11, 13,14,15,17, 19,21,22,23};
        int sgi = 0, off = t2;
        while (off >= cnt[sgi]) { off -= cnt[sgi]; sgi++; }
        const void* p = ps.p[sp[sgi]];
        W[wdst[sgi] + off] = bf ? b2f(((const u16*)p)[off]) : ((const float*)p)[off];
        return;
    }
    if (t < PREP_LUT) {
        int i = t - PREP_BIAS;
        float x0 = i * 0.03125f, x1 = x0 + 0.03125f;
        float t0 = tanhf(x0), t1 = tanhf(x1);
        float s = (t1 - t0) * 32.f;
        float b = fmaf(-s, x0, t0);
        __half hs = __float2half(s), hb = __float2half(b);
        u16 us, ub;
        __builtin_memcpy(&us, &hs, 2); __builtin_memcpy(&ub, &hb, 2);
        gtbl[i] = (u32)ub | ((u32)us << 16);
        return;
    }
    if (t < PREP_TOTAL) cnts[t - PREP_LUT] = 0;
}

// ---------------- graph build (even-padded CSR) ----------------

__global__ void hist_kernel(const int* __restrict__ dst, int* __restrict__ cnts) {
    int e = blockIdx.x * blockDim.x + threadIdx.x;
    if (e < N_EDGES) atomicAdd(&cnts[dst[e]], 1);
}

__global__ void scanA(const int* __restrict__ cnts, int* __restrict__ prow,
                      int* __restrict__ bsum) {
    __shared__ int wsum[16];
    int tid = threadIdx.x, lane = tid & 63, wid = tid >> 6;
    int i0 = blockIdx.x * 2048 + tid * 2;
    int v0 = 0, v1 = 0;
    if (i0 >= 1 && i0 <= N_NODES) v0 = (cnts[i0 - 1] + 1) & ~1;
    if (i0 + 1 <= N_NODES && i0 + 1 >= 1) v1 = (cnts[i0] + 1) & ~1;
    int v = v0 + v1;
#pragma unroll
    for (int off = 1; off < 64; off <<= 1) {
        int t = __shfl_up(v, off, 64);
        if (lane >= off) v += t;
    }
    if (lane == 63) wsum[wid] = v;
    __syncthreads();
    if (tid == 0) { int a = 0; for (int w = 0; w < 16; w++) { a += wsum[w]; wsum[w] = a; } }
    __syncthreads();
    int incl = v + (wid ? wsum[wid - 1] : 0);
    if (i0 <= N_NODES) prow[i0] = incl - v1;
    if (i0 + 1 <= N_NODES) prow[i0 + 1] = incl;
    if (tid == 1023) bsum[blockIdx.x] = incl;   // raw per-block total
}
// cross-block prefix + cursor init + pad-slot marking
__global__ void scanC(const int* __restrict__ bsum, const int* __restrict__ cnts,
                      int* __restrict__ prow, int* __restrict__ cursor,
                      int* __restrict__ srcs) {
    int i = blockIdx.x * 1024 + threadIdx.x;
    if (i > N_NODES) return;
    int nb = (int)(blockIdx.x >> 1);
    int add = 0;
    for (int b = 0; b < nb; b++) add += bsum[b];
    int v = prow[i] + add;
    prow[i] = v;
    if (i < N_NODES) {
        cursor[i] = v;
        int c = cnts[i];
        if (c & 1) srcs[v + c] = -1;   // pad marker for odd-degree nodes
    }
}

__global__ void scatter_kernel(const int* __restrict__ dst, const int* __restrict__ src,
                               int* __restrict__ cursor, int* __restrict__ perm,
                               int* __restrict__ srcs) {
    int e = blockIdx.x * blockDim.x + threadIdx.x;
    if (e >= N_EDGES) return;
    int p = atomicAdd(&cursor[dst[e]], 1);
    perm[e] = p;
    srcs[p] = src[e];
}

// ---------------- MFMA layer building blocks ----------------
// D = Wfrag(A) x ActFrag(B) -> D[n][m]: m = lane&15, n = nt*16 + (lane>>4)*4 + reg.

template<int KT, int NT, int INSTR>
__device__ __forceinline__ void mfma_layer(const u32* ldsin, int lane,
        const short8* __restrict__ Wf, int basef, const float* __restrict__ bias, f32x4* acc) {
    int q = lane >> 4, mr = lane & 15;
#pragma unroll
    for (int nt = 0; nt < NT; nt++) acc[nt] = *(const f32x4*)(bias + nt * 16 + q * 4);
#pragma unroll
    for (int kt = 0; kt < KT; kt++) {
        short8 act = *(const short8*)(ldsin + mr * INSTR + kt * 16 + q * 4);
#pragma unroll
        for (int nt = 0; nt < NT; nt++)
            acc[nt] = mfma16(Wf[(basef + kt * NT + nt) * 64 + lane], act, acc[nt]);
    }
}

template<int KT, int NT>
__device__ __forceinline__ void mfma_layer_reg(const short8* act, int lane,
        const short8* __restrict__ Wf, int basef, const float* __restrict__ bias, f32x4* acc) {
    int q = lane >> 4;
#pragma unroll
    for (int nt = 0; nt < NT; nt++) acc[nt] = *(const f32x4*)(bias + nt * 16 + q * 4);
#pragma unroll
    for (int kt = 0; kt < KT; kt++)
#pragma unroll
        for (int nt = 0; nt < NT; nt++)
            acc[nt] = mfma16(Wf[(basef + kt * NT + nt) * 64 + lane], act[kt], acc[nt]);
}

// b64 activation writes (pairs are address-consecutive)
template<int NT, int OUTSTR>
__device__ __forceinline__ void tanh_pack_lds(const f32x4* acc, u32* ldsout, int lane,
                                              const u32* __restrict__ tbl) {
    int q = lane >> 4, mr = lane & 15;
#pragma unroll
    for (int nt = 0; nt < NT; nt++) {
        f32x4 a = acc[nt];
        u32x2 pb;
        pb.x = pack2(lut_tanh(tbl, a[0]), lut_tanh(tbl, a[1]));
        pb.y = pack2(lut_tanh(tbl, a[2]), lut_tanh(tbl, a[3]));
        *(u32x2*)&ldsout[mr * OUTSTR + nt * 8 + q * 2] = pb;
    }
}

// full-wave zero-fill of the 16x16-dword staging region (stride-36 rows)
__device__ __forceinline__ void zero_stage(u32* B0, int lane) {
#pragma unroll
    for (int it = 0; it < 4; it++) {
        int f = lane + 64 * it;
        B0[(f >> 4) * 36 + (f & 15)] = 0;
    }
}

// ---------------- encoders / MLP / head ----------------

__global__ __launch_bounds__(256) void edge_encoder(const void* nf, const void* ef,
        u32* __restrict__ ebuf, const int* __restrict__ perm, const float* __restrict__ W,
        const short8* __restrict__ Wf, const u32* __restrict__ gtbl) {
    __shared__ u32 lds[4 * 1152];
    __shared__ u32 tbl[TANH_TBL_N];
    bool bf = detect_bf(nf);
    load_tbl(gtbl, tbl);
    int wv = threadIdx.x >> 6, lane = threadIdx.x & 63;
    int q = lane >> 4, mr = lane & 15;
    u32* B0 = lds + wv * 1152;
    u32* B1 = B0 + 576;
    long ebase = (long)blockIdx.x * 64 + wv * 16;
    zero_stage(B0, lane);
    if (lane < 16) {
        long e = ebase + lane;   // N_EDGES % 64 == 0: always valid
        float i0, i1, i2;
        if (bf) { const u16* p = (const u16*)ef + e * 3; i0 = b2f(p[0]); i1 = b2f(p[1]); i2 = b2f(p[2]); }
        else    { const float* p = (const float*)ef + e * 3; i0 = p[0]; i1 = p[1]; i2 = p[2]; }
        u32* row = B0 + lane * 36;
        row[0] = pack2(i0, i1); row[1] = pack2(i2, 0.f);
    }
    WAVE_SYNC();
    f32x4 acc[4];
    mfma_layer<1, 4, 36>(B0, lane, Wf, FR_EE1, W + EE_B0, acc);
    tanh_pack_lds<4, 36>(acc, B1, lane, tbl);
    WAVE_SYNC();
    mfma_layer<2, 4, 36>(B1, lane, Wf, FR_EE2, W + EE_B1, acc);
    tanh_pack_lds<4, 36>(acc, B0, lane, tbl);
    WAVE_SYNC();
    mfma_layer<2, 4, 36>(B0, lane, Wf, FR_EE3, W + EE_B2, acc);
    // final layer: tanh + pack + DIRECT global store from accumulators
    int prw = perm[ebase + mr];
    size_t gb = (size_t)prw * 32 + (size_t)(q * 2);
#pragma unroll
    for (int nt = 0; nt < 4; nt++) {
        u32x2 pb;
        pb.x = pack2(lut_tanh(tbl, acc[nt][0]), lut_tanh(tbl, acc[nt][1]));
        pb.y = pack2(lut_tanh(tbl, acc[nt][2]), lut_tanh(tbl, acc[nt][3]));
        *(u32x2*)&ebuf[gb + nt * 8] = pb;
    }
}

__global__ __launch_bounds__(256) void node_encoder(const void* nf,
        u16* __restrict__ xbf, const float* __restrict__ W,
        const short8* __restrict__ Wf, const u32* __restrict__ gtbl) {
    __shared__ u32 lds[4 * 1152];
    __shared__ u32 tbl[TANH_TBL_N];
    bool bf = detect_bf(nf);
    load_tbl(gtbl, tbl);
    int wv = threadIdx.x >> 6, lane = threadIdx.x & 63;
    int q = lane >> 4, mr = lane & 15;
    u32* B0 = lds + wv * 1152;
    u32* B1 = B0 + 576;
    long nbase = (long)blockIdx.x * 64 + wv * 16;
    zero_stage(B0, lane);
    if (lane < 16) {
        long n = nbase + lane;
        if (n < N_NODES) {
            float in[11];
#pragma unroll
            for (int j = 0; j < 11; j++)
                in[j] = bf ? b2f(((const u16*)nf)[n * 11 + j]) : ((const float*)nf)[n * 11 + j];
            u32* row = B0 + lane * 36;
#pragma unroll
            for (int d = 0; d < 5; d++) row[d] = pack2(in[2 * d], in[2 * d + 1]);
            row[5] = pack2(in[10], 0.f);
        }
    }
    WAVE_SYNC();
    f32x4 acc[4];
    mfma_layer<1, 4, 36>(B0, lane, Wf, FR_NE1, W + NE_B0, acc);
    tanh_pack_lds<4, 36>(acc, B1, lane, tbl);
    WAVE_SYNC();
    mfma_layer<2, 4, 36>(B1, lane, Wf, FR_NE2, W + NE_B1, acc);
    tanh_pack_lds<4, 36>(acc, B0, lane, tbl);
    WAVE_SYNC();
    mfma_layer<2, 4, 36>(B0, lane, Wf, FR_NE3, W + NE_B2, acc);
    long n = nbase + mr;
    if (n < N_NODES) {
#pragma unroll
        for (int nt = 0; nt < 4; nt++) {
            u32x2 pb;
            pb.x = pack2(lut_tanh(tbl, acc[nt][0]), lut_tanh(tbl, acc[nt][1]));
            pb.y = pack2(lut_tanh(tbl, acc[nt][2]), lut_tanh(tbl, acc[nt][3]));
            *(u32x2*)&xbf[n * 64 + nt * 16 + q * 4] = pb;
        }
    }
}

// 2 nodes per wave, 4 edges per iteration (quarter-wave per edge, b64 loads).
// srcs window staged to per-wave LDS; inner loops branchless; pads src=-1 -> w=0.
template<int R>
__global__ __launch_bounds__(256) void aggregate_kernel(
        const u32* __restrict__ xbf32, const u32* __restrict__ ebuf32,
        const int* __restrict__ srcs, const int* __restrict__ prow,
        u32* __restrict__ h64bf32) {
    __shared__ int ldsW[4][64];
    int wv = threadIdx.x >> 6;
    int wid = (int)((blockIdx.x * 256 + threadIdx.x) >> 6);
    int lane = (int)(threadIdx.x & 63);
    int n0 = __builtin_amdgcn_readfirstlane(wid) * 2;
    if (n0 >= N_NODES) return;
    int qt = lane >> 4, h16 = lane & 15;
    int rl = n0 + (lane < 2 ? lane : 2);
    int rv = prow[rl];
    int kb0 = __shfl(rv, 0, 64);
    int kb1 = __shfl(rv, 1, 64);
    int kb2 = __shfl(rv, 2, 64);
    float an[2][4], ad[2][4];
#pragma unroll
    for (int j = 0; j < 2; j++)
#pragma unroll
        for (int f = 0; f < 4; f++) { an[j][f] = 0.f; ad[j][f] = 0.f; }
    for (int wb = kb0; wb < kb2; wb += 64) {
        ldsW[wv][lane] = srcs[wb + lane];
        WAVE_SYNC();
        int we = wb + 64;
        int hi0 = kb1 < we ? kb1 : we;
        int lo1 = kb1 > wb ? kb1 : wb;
        int hi1 = kb2 < we ? kb2 : we;
#pragma unroll 2
        for (int k = wb; k < hi0; k += 4) {
            int e = k + qt;
            int eoc = (e < hi0) ? e : (hi0 - 1);
            int s = ldsW[wv][eoc - wb];
            u32x2 ev = *(const u32x2*)&ebuf32[(size_t)eoc * 32 + 2 * h16];
            u32x2 xv = *(const u32x2*)&xbf32[(size_t)(s > 0 ? s : 0) * 32 + 2 * h16];
            float vf = (e < hi0 && s >= 0) ? 1.f : 0.f;
            float m0 = fmaxf(lo2f(xv.x) + lo2f(ev.x), 0.f) + 1e-7f;
            float m1 = fmaxf(hi2f(xv.x) + hi2f(ev.x), 0.f) + 1e-7f;
            float m2 = fmaxf(lo2f(xv.y) + lo2f(ev.y), 0.f) + 1e-7f;
            float m3 = fmaxf(hi2f(xv.y) + hi2f(ev.y), 0.f) + 1e-7f;
            float w0 = __expf(m0) * vf, w1 = __expf(m1) * vf;
            float w2 = __expf(m2) * vf, w3 = __expf(m3) * vf;
            an[0][0] = fmaf(w0, m0, an[0][0]); ad[0][0] += w0;
            an[0][1] = fmaf(w1, m1, an[0][1]); ad[0][1] += w1;
            an[0][2] = fmaf(w2, m2, an[0][2]); ad[0][2] += w2;
            an[0][3] = fmaf(w3, m3, an[0][3]); ad[0][3] += w3;
        }
#pragma unroll 2
        for (int k = lo1; k < hi1; k += 4) {
            int e = k + qt;
            int eoc = (e < hi1) ? e : (hi1 - 1);
            int s = ldsW[wv][eoc - wb];
            u32x2 ev = *(const u32x2*)&ebuf32[(size_t)eoc * 32 + 2 * h16];
            u32x2 xv = *(const u32x2*)&xbf32[(size_t)(s > 0 ? s : 0) * 32 + 2 * h16];
            float vf = (e < hi1 && s >= 0) ? 1.f : 0.f;
            float m0 = fmaxf(lo2f(xv.x) + lo2f(ev.x), 0.f) + 1e-7f;
            float m1 = fmaxf(hi2f(xv.x) + hi2f(ev.x), 0.f) + 1e-7f;
            float m2 = fmaxf(lo2f(xv.y) + lo2f(ev.y), 0.f) + 1e-7f;
            float m3 = fmaxf(hi2f(xv.y) + hi2f(ev.y), 0.f) + 1e-7f;
            float w0 = __expf(m0) * vf, w1 = __expf(m1) * vf;
            float w2 = __expf(m2) * vf, w3 = __expf(m3) * vf;
            an[1][0] = fmaf(w0, m0, an[1][0]); ad[1][0] += w0;
            an[1][1] = fmaf(w1, m1, an[1][1]); ad[1][1] += w1;
            an[1][2] = fmaf(w2, m2, an[1][2]); ad[1][2] += w2;
            an[1][3] = fmaf(w3, m3, an[1][3]); ad[1][3] += w3;
        }
        WAVE_SYNC();   // drain reads before next window overwrite
    }
#pragma unroll
    for (int j = 0; j < 2; j++) {
#pragma unroll
        for (int f = 0; f < 4; f++) {
            an[j][f] += __shfl_xor(an[j][f], 16, 64);
            an[j][f] += __shfl_xor(an[j][f], 32, 64);
            ad[j][f] += __shfl_xor(ad[j][f], 16, 64);
            ad[j][f] += __shfl_xor(ad[j][f], 32, 64);
        }
        if (qt == 0) {
            float a0 = (ad[j][0] > 0.f) ? __fdividef(an[j][0], ad[j][0]) : 0.f;
            float a1 = (ad[j][1] > 0.f) ? __fdividef(an[j][1], ad[j][1]) : 0.f;
            float a2 = (ad[j][2] > 0.f) ? __fdividef(an[j][2], ad[j][2]) : 0.f;
            float a3 = (ad[j][3] > 0.f) ? __fdividef(an[j][3], ad[j][3]) : 0.f;
            u32x2 xr = *(const u32x2*)&xbf32[(size_t)(n0 + j) * 32 + 2 * h16];
            u32x2 o;
            o.x = pack2(lo2f(xr.x) + a0, hi2f(xr.x) + a1);
            o.y = pack2(lo2f(xr.y) + a2, hi2f(xr.y) + a3);
            *(u32x2*)&h64bf32[(size_t)(n0 + j) * 32 + 2 * h16] = o;
        }
    }
}

// fused node MLP: 64->128 (acts direct from h64bf), LN (shfl), ReLU, 128->64
__global__ __launch_bounds__(256) void mlp_fused(const u16* __restrict__ h64bf,
        u16* __restrict__ xbf,
        const float* __restrict__ W, const short8* __restrict__ Wf, int r) {
    __shared__ u32 lds[4 * 1088];
    int wv = threadIdx.x >> 6, lane = threadIdx.x & 63;
    int q = lane >> 4, mr = lane & 15;
    u32* bufY = lds + wv * 1088;
    long nbase = (long)blockIdx.x * 64 + wv * 16;
    long row = nbase + mr;
    long rc = (row < N_NODES) ? row : (N_NODES - 1);
    short8 act[2];
#pragma unroll
    for (int kt = 0; kt < 2; kt++)
        act[kt] = *(const short8*)&h64bf[rc * 64 + kt * 32 + q * 8];
    f32x4 acc[8];
    mfma_layer_reg<2, 8>(act, lane, Wf, FR_MP0 + r * 16, W + MP_B0 + r * 128, acc);
    float s = 0.f, sq = 0.f;
#pragma unroll
    for (int nt = 0; nt < 8; nt++)
#pragma unroll
        for (int rr = 0; rr < 4; rr++) { float v = acc[nt][rr]; s += v; sq = fmaf(v, v, sq); }
    s += __shfl_xor(s, 16, 64);  s += __shfl_xor(s, 32, 64);
    sq += __shfl_xor(sq, 16, 64); sq += __shfl_xor(sq, 32, 64);
    float mu = s * (1.f / 128.f);
    float var = sq * (1.f / 128.f) - mu * mu;
    float inv = rsqrtf(var + 1e-5f);
    const float* LW = W + LNW_O + r * 128;
    const float* LB = W + LNB_O + r * 128;
#pragma unroll
    for (int nt = 0; nt < 8; nt++) {
        f32x4 lw = *(const f32x4*)(LW + nt * 16 + q * 4);
        f32x4 lb = *(const f32x4*)(LB + nt * 16 + q * 4);
        float u0 = fmaxf(fmaf((acc[nt][0] - mu) * inv, lw[0], lb[0]), 0.f);
        float u1 = fmaxf(fmaf((acc[nt][1] - mu) * inv, lw[1], lb[1]), 0.f);
        float u2 = fmaxf(fmaf((acc[nt][2] - mu) * inv, lw[2], lb[2]), 0.f);
        float u3 = fmaxf(fmaf((acc[nt][3] - mu) * inv, lw[3], lb[3]), 0.f);
        u32x2 pb; pb.x = pack2(u0, u1); pb.y = pack2(u2, u3);
        *(u32x2*)&bufY[mr * 68 + nt * 8 + q * 2] = pb;
    }
    WAVE_SYNC();
    f32x4 acc2[4];
    mfma_layer<4, 4, 68>(bufY, lane, Wf, FR_MP1 + r * 16, W + MP_B1 + r * 64, acc2);
    if (row < N_NODES) {
#pragma unroll
        for (int nt = 0; nt < 4; nt++) {
            f32x4 v = acc2[nt];
            u32x2 pb; pb.x = pack2(v[0], v[1]); pb.y = pack2(v[2], v[3]);
            *(u32x2*)&xbf[row * 64 + nt * 16 + q * 4] = pb;
        }
    }
}

__global__ __launch_bounds__(256) void policy_head(const void* nf,
        const u16* __restrict__ xbf, void* out, const float* __restrict__ W,
        const short8* __restrict__ Wf, const u32* __restrict__ gtbl) {
    __shared__ u32 lds[4 * 576];
    __shared__ u32 tbl[TANH_TBL_N];
    bool bf = detect_bf(nf);
    load_tbl(gtbl, tbl);
    int wv = threadIdx.x >> 6, lane = threadIdx.x & 63;
    int q = lane >> 4, mr = lane & 15;
    u32* bufY = lds + wv * 576;
    long nbase = (long)blockIdx.x * 64 + wv * 16;
    long row = nbase + mr;
    long rc = (row < N_NODES) ? row : (N_NODES - 1);
    short8 act[2];
#pragma unroll
    for (int kt = 0; kt < 2; kt++)
        act[kt] = *(const short8*)&xbf[rc * 64 + kt * 32 + q * 8];
    f32x4 acc[4];
    mfma_layer_reg<2, 4>(act, lane, Wf, FR_PI0, W + PI_B0, acc);
    tanh_pack_lds<4, 36>(acc, bufY, lane, tbl);
    WAVE_SYNC();
    mfma_layer<2, 4, 36>(bufY, lane, Wf, FR_PI1, W + PI_B1, acc);
    float o = 0.f;
#pragma unroll
    for (int nt = 0; nt < 4; nt++) {
        f32x4 w2 = *(const f32x4*)(W + PI_W2 + nt * 16 + q * 4);
#pragma unroll
        for (int rr = 0; rr < 4; rr++) o = fmaf(lut_tanh(tbl, acc[nt][rr]), w2[rr], o);
    }
    o += __shfl_xor(o, 16, 64);
    o += __shfl_xor(o, 32, 64);
    if (lane < 16 && row < N_NODES) {
        float means = 30.f * (o + W[PI_B2]);
        if (bf) ((u16*)out)[row] = f2b(means);
        else    ((float*)out)[row] = means;
    }
}

// ---------------- launch ----------------
extern "C" void kernel_launch(void* const* d_in, const int* in_sizes, int n_in,
                              void* d_out, int out_size, void* d_ws, size_t ws_size,
                              hipStream_t stream) {
    char* ws = (char*)d_ws;
    float* W      = (float*)(ws + OFF_W);
    u16*   Wb     = (u16*)(ws + OFF_WB);
    const short8* Wf = (const short8*)(ws + OFF_WB);
    u32*   gtbl   = (u32*)(ws + OFF_TBL);
    u16*   xb0    = (u16*)(ws + OFF_XB0);
    u16*   xb1    = (u16*)(ws + OFF_XB1);
    u16*   h64bf  = (u16*)(ws + OFF_H64B);
    u32*   h64b32 = (u32*)(ws + OFF_H64B);
    u32*   ebuf32 = (u32*)(ws + OFF_E);
    int*   prow   = (int*)(ws + OFF_ROWPTR);
    int*   cursor = (int*)(ws + OFF_CURSOR);
    int*   cnts   = (int*)(ws + OFF_CNT);
    int*   perm   = (int*)(ws + OFF_PERM);
    int*   srcs   = (int*)(ws + OFF_SRCS);
    int*   bsum   = (int*)(ws + OFF_BSUM);

    const void* nf  = d_in[0];
    const int* ei   = (const int*)d_in[2];
    const int* srcv = ei;
    const int* dstv = ei + N_EDGES;

    Ptrs24 ps;
    for (int k = 0; k < 24; k++) ps.p[k] = d_in[3 + k];
    prep_kernel<<<(PREP_TOTAL + 255) / 256, 256, 0, stream>>>(nf, ps, W, Wb, gtbl, cnts);

    hist_kernel<<<(N_EDGES + 255) / 256, 256, 0, stream>>>(dstv, cnts);
    scanA<<<25, 1024, 0, stream>>>(cnts, prow, bsum);
    scanC<<<(N_NODES + 1024) / 1024, 1024, 0, stream>>>(bsum, cnts, prow, cursor, srcs);
    scatter_kernel<<<(N_EDGES + 255) / 256, 256, 0, stream>>>(dstv, srcv, cursor, perm, srcs);

    node_encoder<<<(N_NODES + 63) / 64, 256, 0, stream>>>(nf, xb0, W, Wf, gtbl);
    edge_encoder<<<N_EDGES / 64, 256, 0, stream>>>(nf, d_in[1], ebuf32, perm, W, Wf, gtbl);

    u16* xbc = xb0; u16* xbn = xb1;
    const int aggBlocks = (N_NODES / 2 * 64) / 256;   // 2 nodes/wave, 4 waves/block
    aggregate_kernel<0><<<aggBlocks, 256, 0, stream>>>((const u32*)xbc, ebuf32, srcs, prow, h64b32);
    mlp_fused<<<(N_NODES + 63) / 64, 256, 0, stream>>>(h64bf, xbn, W, Wf, 0);
    { u16* tb = xbc; xbc = xbn; xbn = tb; }
    aggregate_kernel<1><<<aggBlocks, 256, 0, stream>>>((const u32*)xbc, ebuf32, srcs, prow, h64b32);
    mlp_fused<<<(N_NODES + 63) / 64, 256, 0, stream>>>(h64bf, xbn, W, Wf, 1);
    { u16* tb = xbc; xbc = xbn; xbn = tb; }
    aggregate_kernel<2><<<aggBlocks, 256, 0, stream>>>((const u32*)xbc, ebuf32, srcs, prow, h64b32);
    mlp_fused<<<(N_NODES + 63) / 64, 256, 0, stream>>>(h64bf, xbn, W, Wf, 2);
    { u16* tb = xbc; xbc = xbn; xbn = tb; }

    policy_head<<<(N_NODES + 63) / 64, 256, 0, stream>>>(nf, xbc, d_out, W, Wf, gtbl);
}

// Round 10
// 422.940 us; speedup vs baseline: 1.0388x; 1.0388x over previous
//
#include <hip/hip_runtime.h>
#include <hip/hip_fp16.h>
#include <stdint.h>

#define N_NODES 50000
#define N_EDGES 800000

typedef unsigned short u16;
typedef unsigned int u32;
typedef __attribute__((ext_vector_type(8))) short short8;   // 8 bf16 = A/B frag
typedef __attribute__((ext_vector_type(4))) float f32x4;    // C/D frag
typedef __attribute__((ext_vector_type(4))) u32 u32x4;
typedef __attribute__((ext_vector_type(2))) u32 u32x2;

// wave-private LDS exchange: DS ops in-order per wave; only lgkmcnt drain needed.
#define WAVE_SYNC() asm volatile("s_waitcnt lgkmcnt(0)" ::: "memory")

// ---------------- helpers ----------------
__device__ __forceinline__ float b2f(u16 v) {
    u32 u = ((u32)v) << 16; float f; __builtin_memcpy(&f, &u, 4); return f;
}
__device__ __forceinline__ u16 f2b(float f) {
    u32 u; __builtin_memcpy(&u, &f, 4);
    return (u16)((u + 0x8000u) >> 16);
}
__device__ __forceinline__ float lo2f(u32 p) {
    u32 u = p << 16; float f; __builtin_memcpy(&f, &u, 4); return f;
}
__device__ __forceinline__ float hi2f(u32 p) {
    u32 u = p & 0xffff0000u; float f; __builtin_memcpy(&f, &u, 4); return f;
}
// pack two f32 -> two bf16 (round-half-up) in 3 ops via v_perm_b32
__device__ __forceinline__ u32 pack2(float a, float b) {
    u32 ua, ub; __builtin_memcpy(&ua, &a, 4); __builtin_memcpy(&ub, &b, 4);
    return __builtin_amdgcn_perm(ub + 0x8000u, ua + 0x8000u, 0x07060302u);
}
__device__ __forceinline__ f32x4 mfma16(short8 a, short8 b, f32x4 c) {
    return __builtin_amdgcn_mfma_f32_16x16x32_bf16(a, b, c, 0, 0, 0);
}

// bf16-vs-f32 input detection, inlined per block (wave-uniform result).
__device__ __forceinline__ bool detect_bf(const void* nf) {
    u32 w = ((const u32*)nf)[threadIdx.x & 63];
    u32 lo = w & 0xffffu;
    int e = (int)((lo >> 7) & 0xff);
    int good = ((e >= 118 && e <= 132) || lo == 0) ? 1 : 0;
    unsigned long long b = __ballot(good != 0);
    return __popcll(b) >= 48;
}

// ---- LUT tanh: 256 segments (f16 intercept/slope packed in u32), step 1/32
// over [0,8); y = fma(s, a, b), sign via v_bfi. err ~1e-3 (< bf16 storage noise).
#define TANH_TBL_N 256
__device__ __forceinline__ void load_tbl(const u32* __restrict__ g, u32* tbl) {
    int i = (int)threadIdx.x;
    if (i < TANH_TBL_N) tbl[i] = g[i];
    __syncthreads();
}
__device__ __forceinline__ float lut_tanh(const u32* __restrict__ tbl, float x) {
    float a = __builtin_fabsf(x);
    a = fminf(a, 7.96875f);
    int i = (int)(a * 32.f);
    u32 e = tbl[i];
    __half2 h2; __builtin_memcpy(&h2, &e, 4);
    float b = __half2float(__low2half(h2));
    float s = __half2float(__high2half(h2));
    return copysignf(fmaf(s, a, b), x);
}

// ---------------- f32 weight buffer offsets (biases/LN/head only) ----------------
enum : int {
    NE_B0 = 704,   NE_B1 = 4864,  NE_B2 = 9024,
    EE_B0 = 9280,  EE_B1 = 13440, EE_B2 = 17600,
    MP_B0 = 42240, LNW_O = 42624, LNB_O = 43008, MP_B1 = 67968,
    PI_B0 = 72256, PI_B1 = 76416, PI_W2 = 76480, PI_B2 = 76608,
    W_TOTAL = 76610
};

// fragment-buffer layer bases (frag id; 512 bf16 per frag)
enum : int {
    FR_EE1 = 0, FR_EE2 = 4, FR_EE3 = 12, FR_NE1 = 20, FR_NE2 = 24, FR_NE3 = 32,
    FR_MP0 = 40, FR_MP1 = 88, FR_PI0 = 136, FR_PI1 = 144, FR_TOTAL = 152
};

// ---------------- workspace layout (bytes) ----------------
#define OFF_W       ((size_t)0)
#define OFF_WB      ((size_t)0x61000)      // 152*512*2 = 155648 B
#define OFF_TBL     ((size_t)0x88000)      // 256 u32 = 1 KB
#define OFF_XB0     ((size_t)0x90000)      // 6.4 MB bf16
#define OFF_XB1     ((size_t)0x700000)     // 6.4 MB bf16
#define OFF_H64B    ((size_t)0xE00000)     // 6.4 MB bf16
#define OFF_E       ((size_t)0x1500000)    // ebuf: up to 850k x 64 bf16
#define OFF_ROWPTR  ((size_t)0x8300000)    // prow (padded CSR), N+1 ints
#define OFF_CURSOR  ((size_t)0x8340000)
#define OFF_CNT     ((size_t)0x8380000)
#define OFF_PERM    ((size_t)0x83C0000)
#define OFF_SRCS    ((size_t)0x8700000)    // padded srcs; pads written by scanC
#define OFF_BSUM    ((size_t)0x8A80000)

struct Ptrs24 { const void* p[24]; };
// 0 ne_w0 1 ne_b0 2 ne_w1 3 ne_b1 4 ne_w2 5 ne_b2 6 ee_w0 7 ee_b0 8 ee_w1 9 ee_b1
// 10 ee_w2 11 ee_b2 12 mp_w0 13 mp_b0 14 mp_ln_w 15 mp_ln_b 16 mp_w1 17 mp_b1
// 18 pi_w0 19 pi_b0 20 pi_w1 21 pi_b1 22 pi_w2 23 pi_b2

// ---------------- one-shot prep: frags + biases + LUT + cnts-zero ----------------
#define PREP_FRAG   (FR_TOTAL * 512)          // 77824
#define PREP_BIAS   (PREP_FRAG + 1986)        // 79810
#define PREP_LUT    (PREP_BIAS + TANH_TBL_N)  // 80066
#define PREP_TOTAL  (PREP_LUT + N_NODES)      // 130066

__global__ void prep_kernel(const void* nf, Ptrs24 ps, float* __restrict__ W,
                            u16* __restrict__ Wb, u32* __restrict__ gtbl,
                            int* __restrict__ cnts) {
    bool bf = detect_bf(nf);
    int t = blockIdx.x * blockDim.x + threadIdx.x;
    if (t < PREP_FRAG) {
        // bake bf16 MFMA A-frag directly from source weights (w[n][k] row-major)
        const int base[15] = {FR_EE1,FR_EE2,FR_EE3,FR_NE1,FR_NE2,FR_NE3,
                              FR_MP0,FR_MP0+16,FR_MP0+32, FR_MP1,FR_MP1+16,FR_MP1+32,
                              FR_PI0,FR_PI1,FR_TOTAL};
        const int psrc[14]  = {6,8,10, 0,2,4, 12,12,12, 16,16,16, 18,20};
        const int soff[14]  = {0,0,0, 0,0,0, 0,8192,16384, 0,8192,16384, 0,0};
        const int kreal[14] = {3,64,64, 11,64,64, 64,64,64, 128,128,128, 64,64};
        const int nn[14]    = {64,64,64, 64,64,64, 128,128,128, 64,64,64, 64,64};
        int f = t >> 9, r = t & 511, lane = r >> 3, j = r & 7;
        int l = 0;
        while (f >= base[l + 1]) l++;
        int lf = f - base[l];
        int NT = nn[l] >> 4;
        int kt = lf / NT, nt = lf % NT;
        int k = kt * 32 + (lane >> 4) * 8 + j;
        int n = nt * 16 + (lane & 15);
        float v = 0.f;
        if (k < kreal[l]) {
            long idx = (long)soff[l] + (long)n * kreal[l] + k;
            const void* p = ps.p[psrc[l]];
            v = bf ? b2f(((const u16*)p)[idx]) : ((const float*)p)[idx];
        }
        u32 u; __builtin_memcpy(&u, &v, 4);
        Wb[t] = (u16)((u + 0x7fffu + ((u >> 16) & 1u)) >> 16);   // RNE
        return;
    }
    if (t < PREP_BIAS) {
        int t2 = t - PREP_FRAG;
        const int cnt[14]  = {64,64,64, 64,64,64, 384,384,384,192, 64,64,128,2};
        const int wdst[14] = {NE_B0,NE_B1,NE_B2, EE_B0,EE_B1,EE_B2,
                              MP_B0,LNW_O,LNB_O,MP_B1, PI_B0,PI_B1,PI_W2,PI_B2};
        const int sp[14]   = {1,3,5, 7,9,11, 13,14,15,17, 19,21,22,23};
        int sgi = 0, off = t2;
        while (off >= cnt[sgi]) { off -= cnt[sgi]; sgi++; }
        const void* p = ps.p[sp[sgi]];
        W[wdst[sgi] + off] = bf ? b2f(((const u16*)p)[off]) : ((const float*)p)[off];
        return;
    }
    if (t < PREP_LUT) {
        int i = t - PREP_BIAS;
        float x0 = i * 0.03125f, x1 = x0 + 0.03125f;
        float t0 = tanhf(x0), t1 = tanhf(x1);
        float s = (t1 - t0) * 32.f;
        float b = fmaf(-s, x0, t0);
        __half hs = __float2half(s), hb = __float2half(b);
        u16 us, ub;
        __builtin_memcpy(&us, &hs, 2); __builtin_memcpy(&ub, &hb, 2);
        gtbl[i] = (u32)ub | ((u32)us << 16);
        return;
    }
    if (t < PREP_TOTAL) cnts[t - PREP_LUT] = 0;
}

// ---------------- graph build (even-padded CSR) ----------------

__global__ void hist_kernel(const int* __restrict__ dst, int* __restrict__ cnts) {
    int e = blockIdx.x * blockDim.x + threadIdx.x;
    if (e < N_EDGES) atomicAdd(&cnts[dst[e]], 1);
}

__global__ void scanA(const int* __restrict__ cnts, int* __restrict__ prow,
                      int* __restrict__ bsum) {
    __shared__ int wsum[16];
    int tid = threadIdx.x, lane = tid & 63, wid = tid >> 6;
    int i0 = blockIdx.x * 2048 + tid * 2;
    int v0 = 0, v1 = 0;
    if (i0 >= 1 && i0 <= N_NODES) v0 = (cnts[i0 - 1] + 1) & ~1;
    if (i0 + 1 <= N_NODES && i0 + 1 >= 1) v1 = (cnts[i0] + 1) & ~1;
    int v = v0 + v1;
#pragma unroll
    for (int off = 1; off < 64; off <<= 1) {
        int t = __shfl_up(v, off, 64);
        if (lane >= off) v += t;
    }
    if (lane == 63) wsum[wid] = v;
    __syncthreads();
    if (tid == 0) { int a = 0; for (int w = 0; w < 16; w++) { a += wsum[w]; wsum[w] = a; } }
    __syncthreads();
    int incl = v + (wid ? wsum[wid - 1] : 0);
    if (i0 <= N_NODES) prow[i0] = incl - v1;
    if (i0 + 1 <= N_NODES) prow[i0 + 1] = incl;
    if (tid == 1023) bsum[blockIdx.x] = incl;   // raw per-block total
}
// cross-block prefix + cursor init + pad-slot marking
__global__ void scanC(const int* __restrict__ bsum, const int* __restrict__ cnts,
                      int* __restrict__ prow, int* __restrict__ cursor,
                      int* __restrict__ srcs) {
    int i = blockIdx.x * 1024 + threadIdx.x;
    if (i > N_NODES) return;
    int nb = (int)(blockIdx.x >> 1);
    int add = 0;
    for (int b = 0; b < nb; b++) add += bsum[b];
    int v = prow[i] + add;
    prow[i] = v;
    if (i < N_NODES) {
        cursor[i] = v;
        int c = cnts[i];
        if (c & 1) srcs[v + c] = -1;   // pad marker for odd-degree nodes
    }
}

__global__ void scatter_kernel(const int* __restrict__ dst, const int* __restrict__ src,
                               int* __restrict__ cursor, int* __restrict__ perm,
                               int* __restrict__ srcs) {
    int e = blockIdx.x * blockDim.x + threadIdx.x;
    if (e >= N_EDGES) return;
    int p = atomicAdd(&cursor[dst[e]], 1);
    perm[e] = p;
    srcs[p] = src[e];
}

// ---------------- MFMA layer building blocks ----------------
// D = Wfrag(A) x ActFrag(B) -> D[n][m]: m = lane&15, n = nt*16 + (lane>>4)*4 + reg.

template<int KT, int NT, int INSTR>
__device__ __forceinline__ void mfma_layer(const u32* ldsin, int lane,
        const short8* __restrict__ Wf, int basef, const float* __restrict__ bias, f32x4* acc) {
    int q = lane >> 4, mr = lane & 15;
#pragma unroll
    for (int nt = 0; nt < NT; nt++) acc[nt] = *(const f32x4*)(bias + nt * 16 + q * 4);
#pragma unroll
    for (int kt = 0; kt < KT; kt++) {
        short8 act = *(const short8*)(ldsin + mr * INSTR + kt * 16 + q * 4);
#pragma unroll
        for (int nt = 0; nt < NT; nt++)
            acc[nt] = mfma16(Wf[(basef + kt * NT + nt) * 64 + lane], act, acc[nt]);
    }
}

template<int KT, int NT>
__device__ __forceinline__ void mfma_layer_reg(const short8* act, int lane,
        const short8* __restrict__ Wf, int basef, const float* __restrict__ bias, f32x4* acc) {
    int q = lane >> 4;
#pragma unroll
    for (int nt = 0; nt < NT; nt++) acc[nt] = *(const f32x4*)(bias + nt * 16 + q * 4);
#pragma unroll
    for (int kt = 0; kt < KT; kt++)
#pragma unroll
        for (int nt = 0; nt < NT; nt++)
            acc[nt] = mfma16(Wf[(basef + kt * NT + nt) * 64 + lane], act[kt], acc[nt]);
}

// b64 activation writes (pairs are address-consecutive)
template<int NT, int OUTSTR>
__device__ __forceinline__ void tanh_pack_lds(const f32x4* acc, u32* ldsout, int lane,
                                              const u32* __restrict__ tbl) {
    int q = lane >> 4, mr = lane & 15;
#pragma unroll
    for (int nt = 0; nt < NT; nt++) {
        f32x4 a = acc[nt];
        u32x2 pb;
        pb.x = pack2(lut_tanh(tbl, a[0]), lut_tanh(tbl, a[1]));
        pb.y = pack2(lut_tanh(tbl, a[2]), lut_tanh(tbl, a[3]));
        *(u32x2*)&ldsout[mr * OUTSTR + nt * 8 + q * 2] = pb;
    }
}

// full-wave zero-fill of the 16x16-dword staging region (stride-36 rows)
__device__ __forceinline__ void zero_stage(u32* B0, int lane) {
#pragma unroll
    for (int it = 0; it < 4; it++) {
        int f = lane + 64 * it;
        B0[(f >> 4) * 36 + (f & 15)] = 0;
    }
}

// ---------------- encoders / MLP / head ----------------

#define EDGE_SPLIT_BLOCKS (N_EDGES / 128)   // 6250 blocks per half

__global__ __launch_bounds__(256) void edge_encoder(const void* nf, const void* ef,
        u32* __restrict__ ebuf, const int* __restrict__ perm, const float* __restrict__ W,
        const short8* __restrict__ Wf, const u32* __restrict__ gtbl, int part) {
    __shared__ u32 lds[4 * 1152];
    __shared__ u32 tbl[TANH_TBL_N];
    bool bf = detect_bf(nf);
    load_tbl(gtbl, tbl);
    int wv = threadIdx.x >> 6, lane = threadIdx.x & 63;
    u32* B0 = lds + wv * 1152;
    u32* B1 = B0 + 576;
    long ebase = ((long)blockIdx.x + (long)part * EDGE_SPLIT_BLOCKS) * 64 + wv * 16;
    zero_stage(B0, lane);
    if (lane < 16) {
        long e = ebase + lane;   // N_EDGES % 128 == 0: always valid
        float i0, i1, i2;
        if (bf) { const u16* p = (const u16*)ef + e * 3; i0 = b2f(p[0]); i1 = b2f(p[1]); i2 = b2f(p[2]); }
        else    { const float* p = (const float*)ef + e * 3; i0 = p[0]; i1 = p[1]; i2 = p[2]; }
        u32* row = B0 + lane * 36;
        row[0] = pack2(i0, i1); row[1] = pack2(i2, 0.f);
    }
    WAVE_SYNC();
    f32x4 acc[4];
    mfma_layer<1, 4, 36>(B0, lane, Wf, FR_EE1, W + EE_B0, acc);
    tanh_pack_lds<4, 36>(acc, B1, lane, tbl);
    WAVE_SYNC();
    mfma_layer<2, 4, 36>(B1, lane, Wf, FR_EE2, W + EE_B1, acc);
    tanh_pack_lds<4, 36>(acc, B0, lane, tbl);
    WAVE_SYNC();
    mfma_layer<2, 4, 36>(B0, lane, Wf, FR_EE3, W + EE_B2, acc);
    tanh_pack_lds<4, 36>(acc, B1, lane, tbl);
    WAVE_SYNC();
    // LDS reshape -> wide coalesced stores (16 B/lane): round-8 epilogue
    int ro = lane >> 2, cc = (lane & 3) * 8;
    long e = ebase + ro;
    long prowp = perm[e];
    u32x4 v0 = *(const u32x4*)&B1[ro * 36 + cc];
    u32x4 v1 = *(const u32x4*)&B1[ro * 36 + cc + 4];
    *(u32x4*)&ebuf[prowp * 32 + cc] = v0;
    *(u32x4*)&ebuf[prowp * 32 + cc + 4] = v1;
}

__global__ __launch_bounds__(256) void node_encoder(const void* nf,
        u16* __restrict__ xbf, const float* __restrict__ W,
        const short8* __restrict__ Wf, const u32* __restrict__ gtbl) {
    __shared__ u32 lds[4 * 1152];
    __shared__ u32 tbl[TANH_TBL_N];
    bool bf = detect_bf(nf);
    load_tbl(gtbl, tbl);
    int wv = threadIdx.x >> 6, lane = threadIdx.x & 63;
    int q = lane >> 4, mr = lane & 15;
    u32* B0 = lds + wv * 1152;
    u32* B1 = B0 + 576;
    long nbase = (long)blockIdx.x * 64 + wv * 16;
    zero_stage(B0, lane);
    if (lane < 16) {
        long n = nbase + lane;
        if (n < N_NODES) {
            float in[11];
#pragma unroll
            for (int j = 0; j < 11; j++)
                in[j] = bf ? b2f(((const u16*)nf)[n * 11 + j]) : ((const float*)nf)[n * 11 + j];
            u32* row = B0 + lane * 36;
#pragma unroll
            for (int d = 0; d < 5; d++) row[d] = pack2(in[2 * d], in[2 * d + 1]);
            row[5] = pack2(in[10], 0.f);
        }
    }
    WAVE_SYNC();
    f32x4 acc[4];
    mfma_layer<1, 4, 36>(B0, lane, Wf, FR_NE1, W + NE_B0, acc);
    tanh_pack_lds<4, 36>(acc, B1, lane, tbl);
    WAVE_SYNC();
    mfma_layer<2, 4, 36>(B1, lane, Wf, FR_NE2, W + NE_B1, acc);
    tanh_pack_lds<4, 36>(acc, B0, lane, tbl);
    WAVE_SYNC();
    mfma_layer<2, 4, 36>(B0, lane, Wf, FR_NE3, W + NE_B2, acc);
    long n = nbase + mr;
    if (n < N_NODES) {
#pragma unroll
        for (int nt = 0; nt < 4; nt++) {
            u32x2 pb;
            pb.x = pack2(lut_tanh(tbl, acc[nt][0]), lut_tanh(tbl, acc[nt][1]));
            pb.y = pack2(lut_tanh(tbl, acc[nt][2]), lut_tanh(tbl, acc[nt][3]));
            *(u32x2*)&xbf[n * 64 + nt * 16 + q * 4] = pb;
        }
    }
}

// 2 nodes per wave, 4 edges per iteration (quarter-wave per edge, b64 loads).
// srcs window staged to per-wave LDS; inner loops branchless; pads src=-1 -> w=0.
template<int R>
__global__ __launch_bounds__(256) void aggregate_kernel(
        const u32* __restrict__ xbf32, const u32* __restrict__ ebuf32,
        const int* __restrict__ srcs, const int* __restrict__ prow,
        u32* __restrict__ h64bf32) {
    __shared__ int ldsW[4][64];
    int wv = threadIdx.x >> 6;
    int wid = (int)((blockIdx.x * 256 + threadIdx.x) >> 6);
    int lane = (int)(threadIdx.x & 63);
    int n0 = __builtin_amdgcn_readfirstlane(wid) * 2;
    if (n0 >= N_NODES) return;
    int qt = lane >> 4, h16 = lane & 15;
    int rl = n0 + (lane < 2 ? lane : 2);
    int rv = prow[rl];
    int kb0 = __shfl(rv, 0, 64);
    int kb1 = __shfl(rv, 1, 64);
    int kb2 = __shfl(rv, 2, 64);
    float an[2][4], ad[2][4];
#pragma unroll
    for (int j = 0; j < 2; j++)
#pragma unroll
        for (int f = 0; f < 4; f++) { an[j][f] = 0.f; ad[j][f] = 0.f; }
    for (int wb = kb0; wb < kb2; wb += 64) {
        ldsW[wv][lane] = srcs[wb + lane];
        WAVE_SYNC();
        int we = wb + 64;
        int hi0 = kb1 < we ? kb1 : we;
        int lo1 = kb1 > wb ? kb1 : wb;
        int hi1 = kb2 < we ? kb2 : we;
#pragma unroll 2
        for (int k = wb; k < hi0; k += 4) {
            int e = k + qt;
            int eoc = (e < hi0) ? e : (hi0 - 1);
            int s = ldsW[wv][eoc - wb];
            u32x2 ev = *(const u32x2*)&ebuf32[(size_t)eoc * 32 + 2 * h16];
            u32x2 xv = *(const u32x2*)&xbf32[(size_t)(s > 0 ? s : 0) * 32 + 2 * h16];
            float vf = (e < hi0 && s >= 0) ? 1.f : 0.f;
            float m0 = fmaxf(lo2f(xv.x) + lo2f(ev.x), 0.f) + 1e-7f;
            float m1 = fmaxf(hi2f(xv.x) + hi2f(ev.x), 0.f) + 1e-7f;
            float m2 = fmaxf(lo2f(xv.y) + lo2f(ev.y), 0.f) + 1e-7f;
            float m3 = fmaxf(hi2f(xv.y) + hi2f(ev.y), 0.f) + 1e-7f;
            float w0 = __expf(m0) * vf, w1 = __expf(m1) * vf;
            float w2 = __expf(m2) * vf, w3 = __expf(m3) * vf;
            an[0][0] = fmaf(w0, m0, an[0][0]); ad[0][0] += w0;
            an[0][1] = fmaf(w1, m1, an[0][1]); ad[0][1] += w1;
            an[0][2] = fmaf(w2, m2, an[0][2]); ad[0][2] += w2;
            an[0][3] = fmaf(w3, m3, an[0][3]); ad[0][3] += w3;
        }
#pragma unroll 2
        for (int k = lo1; k < hi1; k += 4) {
            int e = k + qt;
            int eoc = (e < hi1) ? e : (hi1 - 1);
            int s = ldsW[wv][eoc - wb];
            u32x2 ev = *(const u32x2*)&ebuf32[(size_t)eoc * 32 + 2 * h16];
            u32x2 xv = *(const u32x2*)&xbf32[(size_t)(s > 0 ? s : 0) * 32 + 2 * h16];
            float vf = (e < hi1 && s >= 0) ? 1.f : 0.f;
            float m0 = fmaxf(lo2f(xv.x) + lo2f(ev.x), 0.f) + 1e-7f;
            float m1 = fmaxf(hi2f(xv.x) + hi2f(ev.x), 0.f) + 1e-7f;
            float m2 = fmaxf(lo2f(xv.y) + lo2f(ev.y), 0.f) + 1e-7f;
            float m3 = fmaxf(hi2f(xv.y) + hi2f(ev.y), 0.f) + 1e-7f;
            float w0 = __expf(m0) * vf, w1 = __expf(m1) * vf;
            float w2 = __expf(m2) * vf, w3 = __expf(m3) * vf;
            an[1][0] = fmaf(w0, m0, an[1][0]); ad[1][0] += w0;
            an[1][1] = fmaf(w1, m1, an[1][1]); ad[1][1] += w1;
            an[1][2] = fmaf(w2, m2, an[1][2]); ad[1][2] += w2;
            an[1][3] = fmaf(w3, m3, an[1][3]); ad[1][3] += w3;
        }
        WAVE_SYNC();   // drain reads before next window overwrite
    }
#pragma unroll
    for (int j = 0; j < 2; j++) {
#pragma unroll
        for (int f = 0; f < 4; f++) {
            an[j][f] += __shfl_xor(an[j][f], 16, 64);
            an[j][f] += __shfl_xor(an[j][f], 32, 64);
            ad[j][f] += __shfl_xor(ad[j][f], 16, 64);
            ad[j][f] += __shfl_xor(ad[j][f], 32, 64);
        }
        if (qt == 0) {
            float a0 = (ad[j][0] > 0.f) ? __fdividef(an[j][0], ad[j][0]) : 0.f;
            float a1 = (ad[j][1] > 0.f) ? __fdividef(an[j][1], ad[j][1]) : 0.f;
            float a2 = (ad[j][2] > 0.f) ? __fdividef(an[j][2], ad[j][2]) : 0.f;
            float a3 = (ad[j][3] > 0.f) ? __fdividef(an[j][3], ad[j][3]) : 0.f;
            u32x2 xr = *(const u32x2*)&xbf32[(size_t)(n0 + j) * 32 + 2 * h16];
            u32x2 o;
            o.x = pack2(lo2f(xr.x) + a0, hi2f(xr.x) + a1);
            o.y = pack2(lo2f(xr.y) + a2, hi2f(xr.y) + a3);
            *(u32x2*)&h64bf32[(size_t)(n0 + j) * 32 + 2 * h16] = o;
        }
    }
}

// fused node MLP: 64->128 (acts direct from h64bf), LN (shfl), ReLU, 128->64
__global__ __launch_bounds__(256) void mlp_fused(const u16* __restrict__ h64bf,
        u16* __restrict__ xbf,
        const float* __restrict__ W, const short8* __restrict__ Wf, int r) {
    __shared__ u32 lds[4 * 1088];
    int wv = threadIdx.x >> 6, lane = threadIdx.x & 63;
    int q = lane >> 4, mr = lane & 15;
    u32* bufY = lds + wv * 1088;
    long nbase = (long)blockIdx.x * 64 + wv * 16;
    long row = nbase + mr;
    long rc = (row < N_NODES) ? row : (N_NODES - 1);
    short8 act[2];
#pragma unroll
    for (int kt = 0; kt < 2; kt++)
        act[kt] = *(const short8*)&h64bf[rc * 64 + kt * 32 + q * 8];
    f32x4 acc[8];
    mfma_layer_reg<2, 8>(act, lane, Wf, FR_MP0 + r * 16, W + MP_B0 + r * 128, acc);
    float s = 0.f, sq = 0.f;
#pragma unroll
    for (int nt = 0; nt < 8; nt++)
#pragma unroll
        for (int rr = 0; rr < 4; rr++) { float v = acc[nt][rr]; s += v; sq = fmaf(v, v, sq); }
    s += __shfl_xor(s, 16, 64);  s += __shfl_xor(s, 32, 64);
    sq += __shfl_xor(sq, 16, 64); sq += __shfl_xor(sq, 32, 64);
    float mu = s * (1.f / 128.f);
    float var = sq * (1.f / 128.f) - mu * mu;
    float inv = rsqrtf(var + 1e-5f);
    const float* LW = W + LNW_O + r * 128;
    const float* LB = W + LNB_O + r * 128;
#pragma unroll
    for (int nt = 0; nt < 8; nt++) {
        f32x4 lw = *(const f32x4*)(LW + nt * 16 + q * 4);
        f32x4 lb = *(const f32x4*)(LB + nt * 16 + q * 4);
        float u0 = fmaxf(fmaf((acc[nt][0] - mu) * inv, lw[0], lb[0]), 0.f);
        float u1 = fmaxf(fmaf((acc[nt][1] - mu) * inv, lw[1], lb[1]), 0.f);
        float u2 = fmaxf(fmaf((acc[nt][2] - mu) * inv, lw[2], lb[2]), 0.f);
        float u3 = fmaxf(fmaf((acc[nt][3] - mu) * inv, lw[3], lb[3]), 0.f);
        u32x2 pb; pb.x = pack2(u0, u1); pb.y = pack2(u2, u3);
        *(u32x2*)&bufY[mr * 68 + nt * 8 + q * 2] = pb;
    }
    WAVE_SYNC();
    f32x4 acc2[4];
    mfma_layer<4, 4, 68>(bufY, lane, Wf, FR_MP1 + r * 16, W + MP_B1 + r * 64, acc2);
    if (row < N_NODES) {
#pragma unroll
        for (int nt = 0; nt < 4; nt++) {
            f32x4 v = acc2[nt];
            u32x2 pb; pb.x = pack2(v[0], v[1]); pb.y = pack2(v[2], v[3]);
            *(u32x2*)&xbf[row * 64 + nt * 16 + q * 4] = pb;
        }
    }
}

__global__ __launch_bounds__(256) void policy_head(const void* nf,
        const u16* __restrict__ xbf, void* out, const float* __restrict__ W,
        const short8* __restrict__ Wf, const u32* __restrict__ gtbl) {
    __shared__ u32 lds[4 * 576];
    __shared__ u32 tbl[TANH_TBL_N];
    bool bf = detect_bf(nf);
    load_tbl(gtbl, tbl);
    int wv = threadIdx.x >> 6, lane = threadIdx.x & 63;
    int q = lane >> 4, mr = lane & 15;
    u32* bufY = lds + wv * 576;
    long nbase = (long)blockIdx.x * 64 + wv * 16;
    long row = nbase + mr;
    long rc = (row < N_NODES) ? row : (N_NODES - 1);
    short8 act[2];
#pragma unroll
    for (int kt = 0; kt < 2; kt++)
        act[kt] = *(const short8*)&xbf[rc * 64 + kt * 32 + q * 8];
    f32x4 acc[4];
    mfma_layer_reg<2, 4>(act, lane, Wf, FR_PI0, W + PI_B0, acc);
    tanh_pack_lds<4, 36>(acc, bufY, lane, tbl);
    WAVE_SYNC();
    mfma_layer<2, 4, 36>(bufY, lane, Wf, FR_PI1, W + PI_B1, acc);
    float o = 0.f;
#pragma unroll
    for (int nt = 0; nt < 4; nt++) {
        f32x4 w2 = *(const f32x4*)(W + PI_W2 + nt * 16 + q * 4);
#pragma unroll
        for (int rr = 0; rr < 4; rr++) o = fmaf(lut_tanh(tbl, acc[nt][rr]), w2[rr], o);
    }
    o += __shfl_xor(o, 16, 64);
    o += __shfl_xor(o, 32, 64);
    if (lane < 16 && row < N_NODES) {
        float means = 30.f * (o + W[PI_B2]);
        if (bf) ((u16*)out)[row] = f2b(means);
        else    ((float*)out)[row] = means;
    }
}

// ---------------- launch ----------------
extern "C" void kernel_launch(void* const* d_in, const int* in_sizes, int n_in,
                              void* d_out, int out_size, void* d_ws, size_t ws_size,
                              hipStream_t stream) {
    char* ws = (char*)d_ws;
    float* W      = (float*)(ws + OFF_W);
    u16*   Wb     = (u16*)(ws + OFF_WB);
    const short8* Wf = (const short8*)(ws + OFF_WB);
    u32*   gtbl   = (u32*)(ws + OFF_TBL);
    u16*   xb0    = (u16*)(ws + OFF_XB0);
    u16*   xb1    = (u16*)(ws + OFF_XB1);
    u16*   h64bf  = (u16*)(ws + OFF_H64B);
    u32*   h64b32 = (u32*)(ws + OFF_H64B);
    u32*   ebuf32 = (u32*)(ws + OFF_E);
    int*   prow   = (int*)(ws + OFF_ROWPTR);
    int*   cursor = (int*)(ws + OFF_CURSOR);
    int*   cnts   = (int*)(ws + OFF_CNT);
    int*   perm   = (int*)(ws + OFF_PERM);
    int*   srcs   = (int*)(ws + OFF_SRCS);
    int*   bsum   = (int*)(ws + OFF_BSUM);

    const void* nf  = d_in[0];
    const int* ei   = (const int*)d_in[2];
    const int* srcv = ei;
    const int* dstv = ei + N_EDGES;

    Ptrs24 ps;
    for (int k = 0; k < 24; k++) ps.p[k] = d_in[3 + k];
    prep_kernel<<<(PREP_TOTAL + 255) / 256, 256, 0, stream>>>(nf, ps, W, Wb, gtbl, cnts);

    hist_kernel<<<(N_EDGES + 255) / 256, 256, 0, stream>>>(dstv, cnts);
    scanA<<<25, 1024, 0, stream>>>(cnts, prow, bsum);
    scanC<<<(N_NODES + 1024) / 1024, 1024, 0, stream>>>(bsum, cnts, prow, cursor, srcs);
    scatter_kernel<<<(N_EDGES + 255) / 256, 256, 0, stream>>>(dstv, srcv, cursor, perm, srcs);

    node_encoder<<<(N_NODES + 63) / 64, 256, 0, stream>>>(nf, xb0, W, Wf, gtbl);
    edge_encoder<<<EDGE_SPLIT_BLOCKS, 256, 0, stream>>>(nf, d_in[1], ebuf32, perm, W, Wf, gtbl, 0);
    edge_encoder<<<EDGE_SPLIT_BLOCKS, 256, 0, stream>>>(nf, d_in[1], ebuf32, perm, W, Wf, gtbl, 1);

    u16* xbc = xb0; u16* xbn = xb1;
    const int aggBlocks = (N_NODES / 2 * 64) / 256;   // 2 nodes/wave, 4 waves/block
    aggregate_kernel<0><<<aggBlocks, 256, 0, stream>>>((const u32*)xbc, ebuf32, srcs, prow, h64b32);
    mlp_fused<<<(N_NODES + 63) / 64, 256, 0, stream>>>(h64bf, xbn, W, Wf, 0);
    { u16* tb = xbc; xbc = xbn; xbn = tb; }
    aggregate_kernel<1><<<aggBlocks, 256, 0, stream>>>((const u32*)xbc, ebuf32, srcs, prow, h64b32);
    mlp_fused<<<(N_NODES + 63) / 64, 256, 0, stream>>>(h64bf, xbn, W, Wf, 1);
    { u16* tb = xbc; xbc = xbn; xbn = tb; }
    aggregate_kernel<2><<<aggBlocks, 256, 0, stream>>>((const u32*)xbc, ebuf32, srcs, prow, h64b32);
    mlp_fused<<<(N_NODES + 63) / 64, 256, 0, stream>>>(h64bf, xbn, W, Wf, 2);
    { u16* tb = xbc; xbc = xbn; xbn = tb; }

    policy_head<<<(N_NODES + 63) / 64, 256, 0, stream>>>(nf, xbc, d_out, W, Wf, gtbl);
}

// Round 11
// 417.297 us; speedup vs baseline: 1.0529x; 1.0135x over previous
//
#include <hip/hip_runtime.h>
#include <hip/hip_fp16.h>
#include <stdint.h>

#define N_NODES 50000
#define N_EDGES 800000
#define SEG 16
#define M_ITEMS (SEG * N_NODES)   // 800000 scan items

typedef unsigned short u16;
typedef unsigned int u32;
typedef __attribute__((ext_vector_type(8))) short short8;   // 8 bf16 = A/B frag
typedef __attribute__((ext_vector_type(4))) float f32x4;    // C/D frag
typedef __attribute__((ext_vector_type(4))) u32 u32x4;
typedef __attribute__((ext_vector_type(2))) u32 u32x2;

// wave-private LDS exchange: DS ops in-order per wave; only lgkmcnt drain needed.
#define WAVE_SYNC() asm volatile("s_waitcnt lgkmcnt(0)" ::: "memory")

// ---------------- helpers ----------------
__device__ __forceinline__ float b2f(u16 v) {
    u32 u = ((u32)v) << 16; float f; __builtin_memcpy(&f, &u, 4); return f;
}
__device__ __forceinline__ u16 f2b(float f) {
    u32 u; __builtin_memcpy(&u, &f, 4);
    return (u16)((u + 0x8000u) >> 16);
}
__device__ __forceinline__ float lo2f(u32 p) {
    u32 u = p << 16; float f; __builtin_memcpy(&f, &u, 4); return f;
}
__device__ __forceinline__ float hi2f(u32 p) {
    u32 u = p & 0xffff0000u; float f; __builtin_memcpy(&f, &u, 4); return f;
}
// pack two f32 -> two bf16 (round-half-up) in 3 ops via v_perm_b32
__device__ __forceinline__ u32 pack2(float a, float b) {
    u32 ua, ub; __builtin_memcpy(&ua, &a, 4); __builtin_memcpy(&ub, &b, 4);
    return __builtin_amdgcn_perm(ub + 0x8000u, ua + 0x8000u, 0x07060302u);
}
__device__ __forceinline__ f32x4 mfma16(short8 a, short8 b, f32x4 c) {
    return __builtin_amdgcn_mfma_f32_16x16x32_bf16(a, b, c, 0, 0, 0);
}

// bf16-vs-f32 input detection, inlined per block (wave-uniform result).
__device__ __forceinline__ bool detect_bf(const void* nf) {
    u32 w = ((const u32*)nf)[threadIdx.x & 63];
    u32 lo = w & 0xffffu;
    int e = (int)((lo >> 7) & 0xff);
    int good = ((e >= 118 && e <= 132) || lo == 0) ? 1 : 0;
    unsigned long long b = __ballot(good != 0);
    return __popcll(b) >= 48;
}

// ---- LUT tanh: 256 segments (f16 intercept/slope packed in u32), step 1/32
// over [0,8); y = fma(s, a, b), sign via v_bfi. err ~1e-3 (< bf16 storage noise).
#define TANH_TBL_N 256
__device__ __forceinline__ void load_tbl(const u32* __restrict__ g, u32* tbl) {
    int i = (int)threadIdx.x;
    if (i < TANH_TBL_N) tbl[i] = g[i];
    __syncthreads();
}
__device__ __forceinline__ float lut_tanh(const u32* __restrict__ tbl, float x) {
    float a = __builtin_fabsf(x);
    a = fminf(a, 7.96875f);
    int i = (int)(a * 32.f);
    u32 e = tbl[i];
    __half2 h2; __builtin_memcpy(&h2, &e, 4);
    float b = __half2float(__low2half(h2));
    float s = __half2float(__high2half(h2));
    return copysignf(fmaf(s, a, b), x);
}

// ---------------- f32 weight buffer offsets (biases/LN/head only) ----------------
enum : int {
    NE_B0 = 704,   NE_B1 = 4864,  NE_B2 = 9024,
    EE_B0 = 9280,  EE_B1 = 13440, EE_B2 = 17600,
    MP_B0 = 42240, LNW_O = 42624, LNB_O = 43008, MP_B1 = 67968,
    PI_B0 = 72256, PI_B1 = 76416, PI_W2 = 76480, PI_B2 = 76608,
    W_TOTAL = 76610
};

// fragment-buffer layer bases (frag id; 512 bf16 per frag)
enum : int {
    FR_EE1 = 0, FR_EE2 = 4, FR_EE3 = 12, FR_NE1 = 20, FR_NE2 = 24, FR_NE3 = 32,
    FR_MP0 = 40, FR_MP1 = 88, FR_PI0 = 136, FR_PI1 = 144, FR_TOTAL = 152
};

// ---------------- workspace layout (bytes) ----------------
#define OFF_W       ((size_t)0)
#define OFF_WB      ((size_t)0x61000)      // 152*512*2 = 155648 B
#define OFF_TBL     ((size_t)0x88000)      // 256 u32 = 1 KB
#define OFF_XB0     ((size_t)0x90000)      // 6.4 MB bf16
#define OFF_XB1     ((size_t)0x700000)     // 6.4 MB bf16
#define OFF_H64B    ((size_t)0xE00000)     // 6.4 MB bf16
#define OFF_E       ((size_t)0x1500000)    // ebuf: up to 850k x 64 bf16
#define OFF_PRA     ((size_t)0x8300000)    // prowArr, (M_ITEMS+1) ints = 3.2 MB
#define OFF_CNT16   ((size_t)0x8700000)    // cnt16, M_ITEMS ints = 3.2 MB
#define OFF_CNTT    ((size_t)0x8B00000)    // per-node raw degree, 200 KB
#define OFF_PERM    ((size_t)0x8C00000)    // 3.2 MB
#define OFF_RANK    ((size_t)0x9000000)    // 3.2 MB
#define OFF_SRCS    ((size_t)0x9400000)    // padded srcs, 851968 ints
#define OFF_BSUM    ((size_t)0x9780000)    // 391 ints

struct Ptrs24 { const void* p[24]; };
// 0 ne_w0 1 ne_b0 2 ne_w1 3 ne_b1 4 ne_w2 5 ne_b2 6 ee_w0 7 ee_b0 8 ee_w1 9 ee_b1
// 10 ee_w2 11 ee_b2 12 mp_w0 13 mp_b0 14 mp_ln_w 15 mp_ln_b 16 mp_w1 17 mp_b1
// 18 pi_w0 19 pi_b0 20 pi_w1 21 pi_b1 22 pi_w2 23 pi_b2

// ---------------- one-shot prep: frags + biases + LUT + cnt16-zero ----------------
#define PREP_FRAG   (FR_TOTAL * 512)          // 77824
#define PREP_BIAS   (PREP_FRAG + 1986)        // 79810
#define PREP_LUT    (PREP_BIAS + TANH_TBL_N)  // 80066
#define PREP_TOTAL  (PREP_LUT + M_ITEMS)      // 880066

__global__ void prep_kernel(const void* nf, Ptrs24 ps, float* __restrict__ W,
                            u16* __restrict__ Wb, u32* __restrict__ gtbl,
                            int* __restrict__ cnt16) {
    bool bf = detect_bf(nf);
    int t = blockIdx.x * blockDim.x + threadIdx.x;
    if (t < PREP_FRAG) {
        // bake bf16 MFMA A-frag directly from source weights (w[n][k] row-major)
        const int base[15] = {FR_EE1,FR_EE2,FR_EE3,FR_NE1,FR_NE2,FR_NE3,
                              FR_MP0,FR_MP0+16,FR_MP0+32, FR_MP1,FR_MP1+16,FR_MP1+32,
                              FR_PI0,FR_PI1,FR_TOTAL};
        const int psrc[14]  = {6,8,10, 0,2,4, 12,12,12, 16,16,16, 18,20};
        const int soff[14]  = {0,0,0, 0,0,0, 0,8192,16384, 0,8192,16384, 0,0};
        const int kreal[14] = {3,64,64, 11,64,64, 64,64,64, 128,128,128, 64,64};
        const int nn[14]    = {64,64,64, 64,64,64, 128,128,128, 64,64,64, 64,64};
        int f = t >> 9, r = t & 511, lane = r >> 3, j = r & 7;
        int l = 0;
        while (f >= base[l + 1]) l++;
        int lf = f - base[l];
        int NT = nn[l] >> 4;
        int kt = lf / NT, nt = lf % NT;
        int k = kt * 32 + (lane >> 4) * 8 + j;
        int n = nt * 16 + (lane & 15);
        float v = 0.f;
        if (k < kreal[l]) {
            long idx = (long)soff[l] + (long)n * kreal[l] + k;
            const void* p = ps.p[psrc[l]];
            v = bf ? b2f(((const u16*)p)[idx]) : ((const float*)p)[idx];
        }
        u32 u; __builtin_memcpy(&u, &v, 4);
        Wb[t] = (u16)((u + 0x7fffu + ((u >> 16) & 1u)) >> 16);   // RNE
        return;
    }
    if (t < PREP_BIAS) {
        int t2 = t - PREP_FRAG;
        const int cnt[14]  = {64,64,64, 64,64,64, 384,384,384,192, 64,64,128,2};
        const int wdst[14] = {NE_B0,NE_B1,NE_B2, EE_B0,EE_B1,EE_B2,
                              MP_B0,LNW_O,LNB_O,MP_B1, PI_B0,PI_B1,PI_W2,PI_B2};
        const int sp[14]   = {1,3,5, 7,9,11, 13,14,15,17, 19,21,22,23};
        int sgi = 0, off = t2;
        while (off >= cnt[sgi]) { off -= cnt[sgi]; sgi++; }
        const void* p = ps.p[sp[sgi]];
        W[wdst[sgi] + off] = bf ? b2f(((const u16*)p)[off]) : ((const float*)p)[off];
        return;
    }
    if (t < PREP_LUT) {
        int i = t - PREP_BIAS;
        float x0 = i * 0.03125f, x1 = x0 + 0.03125f;
        float t0 = tanhf(x0), t1 = tanhf(x1);
        float s = (t1 - t0) * 32.f;
        float b = fmaf(-s, x0, t0);
        __half hs = __float2half(s), hb = __float2half(b);
        u16 us, ub;
        __builtin_memcpy(&us, &hs, 2); __builtin_memcpy(&ub, &hb, 2);
        gtbl[i] = (u32)ub | ((u32)us << 16);
        return;
    }
    if (t < PREP_TOTAL) cnt16[t - PREP_LUT] = 0;
}

// ---------------- graph build: segmented rank + atomic-free scatter ----------------

// hist: within-(dst,segment) rank via atomic-with-return; contention ~1.3
__global__ void hist_kernel(const int* __restrict__ dst, int* __restrict__ cnt16,
                            int* __restrict__ rank) {
    int e = blockIdx.x * blockDim.x + threadIdx.x;
    if (e >= N_EDGES) return;
    int g = e >> 16;
    rank[e] = atomicAdd(&cnt16[dst[e] * SEG + g], 1);
}

// per-node total + even-pad applied to last segment slot
__global__ void padfix_kernel(int* __restrict__ cnt16, int* __restrict__ cntTot) {
    int d = blockIdx.x * blockDim.x + threadIdx.x;
    if (d >= N_NODES) return;
    int C = 0;
#pragma unroll
    for (int g = 0; g < SEG; g++) C += cnt16[d * SEG + g];
    cntTot[d] = C;
    if (C & 1) cnt16[d * SEG + SEG - 1] += 1;
}

// scanA over M_ITEMS+1: pra[i] = sum_{j<i} cnt16[j]
__global__ void scanA(const int* __restrict__ cnt16, int* __restrict__ pra,
                      int* __restrict__ bsum) {
    __shared__ int wsum[16];
    int tid = threadIdx.x, lane = tid & 63, wid = tid >> 6;
    int i0 = blockIdx.x * 2048 + tid * 2;
    int v0 = (i0 >= 1 && i0 <= M_ITEMS) ? cnt16[i0 - 1] : 0;
    int v1 = (i0 + 1 <= M_ITEMS) ? cnt16[i0] : 0;
    int v = v0 + v1;
#pragma unroll
    for (int off = 1; off < 64; off <<= 1) {
        int t = __shfl_up(v, off, 64);
        if (lane >= off) v += t;
    }
    if (lane == 63) wsum[wid] = v;
    __syncthreads();
    if (tid == 0) { int a = 0; for (int w = 0; w < 16; w++) { a += wsum[w]; wsum[w] = a; } }
    __syncthreads();
    int incl = v + (wid ? wsum[wid - 1] : 0);
    if (i0 <= M_ITEMS) pra[i0] = incl - v1;
    if (i0 + 1 <= M_ITEMS) pra[i0 + 1] = incl;
    if (tid == 1023) bsum[blockIdx.x] = incl;   // raw block total
}

// scan the 391 block totals (one wave, chunked)
__global__ void scanB(int* __restrict__ bsum, int nb) {
    int lane = (int)threadIdx.x;
    int carry = 0;
    for (int base = 0; base < nb; base += 64) {
        int v = (base + lane < nb) ? bsum[base + lane] : 0;
#pragma unroll
        for (int off = 1; off < 64; off <<= 1) {
            int t = __shfl_up(v, off, 64);
            if (lane >= off) v += t;
        }
        int tot = __shfl(v, 63, 64);
        if (base + lane < nb) bsum[base + lane] = v + carry;
        carry += tot;
    }
}

// apply cross-block prefix + mark pad slots in srcs
__global__ void scanC(const int* __restrict__ bsum, const int* __restrict__ cntTot,
                      int* __restrict__ pra, int* __restrict__ srcs) {
    int i = blockIdx.x * 1024 + threadIdx.x;
    if (i > M_ITEMS) return;
    int b = i >> 11;
    int v = pra[i] + (b ? bsum[b - 1] : 0);
    pra[i] = v;
    if (i < M_ITEMS && (i & (SEG - 1)) == 0) {
        int d = i / SEG;
        int C = cntTot[d];
        if (C & 1) srcs[v + C] = -1;   // pad marker for odd-degree nodes
    }
}

// atomic-free scatter: p = base(dst,seg) + rank; stores are fire-and-forget
__global__ void scatter_kernel(const int* __restrict__ dst, const int* __restrict__ src,
                               const int* __restrict__ rank, const int* __restrict__ pra,
                               int* __restrict__ perm, int* __restrict__ srcs) {
    int e = blockIdx.x * blockDim.x + threadIdx.x;
    if (e >= N_EDGES) return;
    int g = e >> 16;
    int p = pra[dst[e] * SEG + g] + rank[e];
    perm[e] = p;
    srcs[p] = src[e];
}

// ---------------- MFMA layer building blocks ----------------
// D = Wfrag(A) x ActFrag(B) -> D[n][m]: m = lane&15, n = nt*16 + (lane>>4)*4 + reg.

template<int KT, int NT, int INSTR>
__device__ __forceinline__ void mfma_layer(const u32* ldsin, int lane,
        const short8* __restrict__ Wf, int basef, const float* __restrict__ bias, f32x4* acc) {
    int q = lane >> 4, mr = lane & 15;
#pragma unroll
    for (int nt = 0; nt < NT; nt++) acc[nt] = *(const f32x4*)(bias + nt * 16 + q * 4);
#pragma unroll
    for (int kt = 0; kt < KT; kt++) {
        short8 act = *(const short8*)(ldsin + mr * INSTR + kt * 16 + q * 4);
#pragma unroll
        for (int nt = 0; nt < NT; nt++)
            acc[nt] = mfma16(Wf[(basef + kt * NT + nt) * 64 + lane], act, acc[nt]);
    }
}

template<int KT, int NT>
__device__ __forceinline__ void mfma_layer_reg(const short8* act, int lane,
        const short8* __restrict__ Wf, int basef, const float* __restrict__ bias, f32x4* acc) {
    int q = lane >> 4;
#pragma unroll
    for (int nt = 0; nt < NT; nt++) acc[nt] = *(const f32x4*)(bias + nt * 16 + q * 4);
#pragma unroll
    for (int kt = 0; kt < KT; kt++)
#pragma unroll
        for (int nt = 0; nt < NT; nt++)
            acc[nt] = mfma16(Wf[(basef + kt * NT + nt) * 64 + lane], act[kt], acc[nt]);
}

// b64 activation writes (pairs are address-consecutive)
template<int NT, int OUTSTR>
__device__ __forceinline__ void tanh_pack_lds(const f32x4* acc, u32* ldsout, int lane,
                                              const u32* __restrict__ tbl) {
    int q = lane >> 4, mr = lane & 15;
#pragma unroll
    for (int nt = 0; nt < NT; nt++) {
        f32x4 a = acc[nt];
        u32x2 pb;
        pb.x = pack2(lut_tanh(tbl, a[0]), lut_tanh(tbl, a[1]));
        pb.y = pack2(lut_tanh(tbl, a[2]), lut_tanh(tbl, a[3]));
        *(u32x2*)&ldsout[mr * OUTSTR + nt * 8 + q * 2] = pb;
    }
}

// full-wave zero-fill of the 16x16-dword staging region (stride-36 rows)
__device__ __forceinline__ void zero_stage(u32* B0, int lane) {
#pragma unroll
    for (int it = 0; it < 4; it++) {
        int f = lane + 64 * it;
        B0[(f >> 4) * 36 + (f & 15)] = 0;
    }
}

// ---------------- encoders / MLP / head ----------------

#define EDGE_SPLIT_BLOCKS (N_EDGES / 128)   // 6250 blocks per half

__global__ __launch_bounds__(256) void edge_encoder(const void* nf, const void* ef,
        u32* __restrict__ ebuf, const int* __restrict__ perm, const float* __restrict__ W,
        const short8* __restrict__ Wf, const u32* __restrict__ gtbl, int part) {
    __shared__ u32 lds[4 * 1152];
    __shared__ u32 tbl[TANH_TBL_N];
    bool bf = detect_bf(nf);
    load_tbl(gtbl, tbl);
    int wv = threadIdx.x >> 6, lane = threadIdx.x & 63;
    u32* B0 = lds + wv * 1152;
    u32* B1 = B0 + 576;
    long ebase = ((long)blockIdx.x + (long)part * EDGE_SPLIT_BLOCKS) * 64 + wv * 16;
    zero_stage(B0, lane);
    if (lane < 16) {
        long e = ebase + lane;   // N_EDGES % 128 == 0: always valid
        float i0, i1, i2;
        if (bf) { const u16* p = (const u16*)ef + e * 3; i0 = b2f(p[0]); i1 = b2f(p[1]); i2 = b2f(p[2]); }
        else    { const float* p = (const float*)ef + e * 3; i0 = p[0]; i1 = p[1]; i2 = p[2]; }
        u32* row = B0 + lane * 36;
        row[0] = pack2(i0, i1); row[1] = pack2(i2, 0.f);
    }
    WAVE_SYNC();
    f32x4 acc[4];
    mfma_layer<1, 4, 36>(B0, lane, Wf, FR_EE1, W + EE_B0, acc);
    tanh_pack_lds<4, 36>(acc, B1, lane, tbl);
    WAVE_SYNC();
    mfma_layer<2, 4, 36>(B1, lane, Wf, FR_EE2, W + EE_B1, acc);
    tanh_pack_lds<4, 36>(acc, B0, lane, tbl);
    WAVE_SYNC();
    mfma_layer<2, 4, 36>(B0, lane, Wf, FR_EE3, W + EE_B2, acc);
    tanh_pack_lds<4, 36>(acc, B1, lane, tbl);
    WAVE_SYNC();
    // LDS reshape -> wide coalesced stores (16 B/lane)
    int ro = lane >> 2, cc = (lane & 3) * 8;
    long e = ebase + ro;
    long prowp = perm[e];
    u32x4 v0 = *(const u32x4*)&B1[ro * 36 + cc];
    u32x4 v1 = *(const u32x4*)&B1[ro * 36 + cc + 4];
    *(u32x4*)&ebuf[prowp * 32 + cc] = v0;
    *(u32x4*)&ebuf[prowp * 32 + cc + 4] = v1;
}

__global__ __launch_bounds__(256) void node_encoder(const void* nf,
        u16* __restrict__ xbf, const float* __restrict__ W,
        const short8* __restrict__ Wf, const u32* __restrict__ gtbl) {
    __shared__ u32 lds[4 * 1152];
    __shared__ u32 tbl[TANH_TBL_N];
    bool bf = detect_bf(nf);
    load_tbl(gtbl, tbl);
    int wv = threadIdx.x >> 6, lane = threadIdx.x & 63;
    int q = lane >> 4, mr = lane & 15;
    u32* B0 = lds + wv * 1152;
    u32* B1 = B0 + 576;
    long nbase = (long)blockIdx.x * 64 + wv * 16;
    zero_stage(B0, lane);
    if (lane < 16) {
        long n = nbase + lane;
        if (n < N_NODES) {
            float in[11];
#pragma unroll
            for (int j = 0; j < 11; j++)
                in[j] = bf ? b2f(((const u16*)nf)[n * 11 + j]) : ((const float*)nf)[n * 11 + j];
            u32* row = B0 + lane * 36;
#pragma unroll
            for (int d = 0; d < 5; d++) row[d] = pack2(in[2 * d], in[2 * d + 1]);
            row[5] = pack2(in[10], 0.f);
        }
    }
    WAVE_SYNC();
    f32x4 acc[4];
    mfma_layer<1, 4, 36>(B0, lane, Wf, FR_NE1, W + NE_B0, acc);
    tanh_pack_lds<4, 36>(acc, B1, lane, tbl);
    WAVE_SYNC();
    mfma_layer<2, 4, 36>(B1, lane, Wf, FR_NE2, W + NE_B1, acc);
    tanh_pack_lds<4, 36>(acc, B0, lane, tbl);
    WAVE_SYNC();
    mfma_layer<2, 4, 36>(B0, lane, Wf, FR_NE3, W + NE_B2, acc);
    long n = nbase + mr;
    if (n < N_NODES) {
#pragma unroll
        for (int nt = 0; nt < 4; nt++) {
            u32x2 pb;
            pb.x = pack2(lut_tanh(tbl, acc[nt][0]), lut_tanh(tbl, acc[nt][1]));
            pb.y = pack2(lut_tanh(tbl, acc[nt][2]), lut_tanh(tbl, acc[nt][3]));
            *(u32x2*)&xbf[n * 64 + nt * 16 + q * 4] = pb;
        }
    }
}

// 2 nodes per wave, 4 edges per iteration (quarter-wave per edge, b64 loads).
// srcs window staged to per-wave LDS; inner loops branchless; pads src=-1 -> w=0.
#define AGG_HALF_WAVES (N_NODES / 4)   // 12500 waves per half
template<int R>
__global__ __launch_bounds__(256) void aggregate_kernel(
        const u32* __restrict__ xbf32, const u32* __restrict__ ebuf32,
        const int* __restrict__ srcs, const int* __restrict__ pra,
        u32* __restrict__ h64bf32, int part) {
    __shared__ int ldsW[4][64];
    int wv = threadIdx.x >> 6;
    int wid = (int)((blockIdx.x * 256 + threadIdx.x) >> 6) + part * AGG_HALF_WAVES;
    int lane = (int)(threadIdx.x & 63);
    int n0 = __builtin_amdgcn_readfirstlane(wid) * 2;
    if (n0 >= N_NODES) return;
    int qt = lane >> 4, h16 = lane & 15;
    int rl = n0 + (lane < 2 ? lane : 2);
    int rv = pra[rl * SEG];
    int kb0 = __shfl(rv, 0, 64);
    int kb1 = __shfl(rv, 1, 64);
    int kb2 = __shfl(rv, 2, 64);
    float an[2][4], ad[2][4];
#pragma unroll
    for (int j = 0; j < 2; j++)
#pragma unroll
        for (int f = 0; f < 4; f++) { an[j][f] = 0.f; ad[j][f] = 0.f; }
    for (int wb = kb0; wb < kb2; wb += 64) {
        ldsW[wv][lane] = srcs[wb + lane];
        WAVE_SYNC();
        int we = wb + 64;
        int hi0 = kb1 < we ? kb1 : we;
        int lo1 = kb1 > wb ? kb1 : wb;
        int hi1 = kb2 < we ? kb2 : we;
#pragma unroll 2
        for (int k = wb; k < hi0; k += 4) {
            int e = k + qt;
            int eoc = (e < hi0) ? e : (hi0 - 1);
            int s = ldsW[wv][eoc - wb];
            u32x2 ev = *(const u32x2*)&ebuf32[(size_t)eoc * 32 + 2 * h16];
            u32x2 xv = *(const u32x2*)&xbf32[(size_t)(s > 0 ? s : 0) * 32 + 2 * h16];
            float vf = (e < hi0 && s >= 0) ? 1.f : 0.f;
            float m0 = fmaxf(lo2f(xv.x) + lo2f(ev.x), 0.f) + 1e-7f;
            float m1 = fmaxf(hi2f(xv.x) + hi2f(ev.x), 0.f) + 1e-7f;
            float m2 = fmaxf(lo2f(xv.y) + lo2f(ev.y), 0.f) + 1e-7f;
            float m3 = fmaxf(hi2f(xv.y) + hi2f(ev.y), 0.f) + 1e-7f;
            float w0 = __expf(m0) * vf, w1 = __expf(m1) * vf;
            float w2 = __expf(m2) * vf, w3 = __expf(m3) * vf;
            an[0][0] = fmaf(w0, m0, an[0][0]); ad[0][0] += w0;
            an[0][1] = fmaf(w1, m1, an[0][1]); ad[0][1] += w1;
            an[0][2] = fmaf(w2, m2, an[0][2]); ad[0][2] += w2;
            an[0][3] = fmaf(w3, m3, an[0][3]); ad[0][3] += w3;
        }
#pragma unroll 2
        for (int k = lo1; k < hi1; k += 4) {
            int e = k + qt;
            int eoc = (e < hi1) ? e : (hi1 - 1);
            int s = ldsW[wv][eoc - wb];
            u32x2 ev = *(const u32x2*)&ebuf32[(size_t)eoc * 32 + 2 * h16];
            u32x2 xv = *(const u32x2*)&xbf32[(size_t)(s > 0 ? s : 0) * 32 + 2 * h16];
            float vf = (e < hi1 && s >= 0) ? 1.f : 0.f;
            float m0 = fmaxf(lo2f(xv.x) + lo2f(ev.x), 0.f) + 1e-7f;
            float m1 = fmaxf(hi2f(xv.x) + hi2f(ev.x), 0.f) + 1e-7f;
            float m2 = fmaxf(lo2f(xv.y) + lo2f(ev.y), 0.f) + 1e-7f;
            float m3 = fmaxf(hi2f(xv.y) + hi2f(ev.y), 0.f) + 1e-7f;
            float w0 = __expf(m0) * vf, w1 = __expf(m1) * vf;
            float w2 = __expf(m2) * vf, w3 = __expf(m3) * vf;
            an[1][0] = fmaf(w0, m0, an[1][0]); ad[1][0] += w0;
            an[1][1] = fmaf(w1, m1, an[1][1]); ad[1][1] += w1;
            an[1][2] = fmaf(w2, m2, an[1][2]); ad[1][2] += w2;
            an[1][3] = fmaf(w3, m3, an[1][3]); ad[1][3] += w3;
        }
        WAVE_SYNC();   // drain reads before next window overwrite
    }
#pragma unroll
    for (int j = 0; j < 2; j++) {
#pragma unroll
        for (int f = 0; f < 4; f++) {
            an[j][f] += __shfl_xor(an[j][f], 16, 64);
            an[j][f] += __shfl_xor(an[j][f], 32, 64);
            ad[j][f] += __shfl_xor(ad[j][f], 16, 64);
            ad[j][f] += __shfl_xor(ad[j][f], 32, 64);
        }
        if (qt == 0) {
            float a0 = (ad[j][0] > 0.f) ? __fdividef(an[j][0], ad[j][0]) : 0.f;
            float a1 = (ad[j][1] > 0.f) ? __fdividef(an[j][1], ad[j][1]) : 0.f;
            float a2 = (ad[j][2] > 0.f) ? __fdividef(an[j][2], ad[j][2]) : 0.f;
            float a3 = (ad[j][3] > 0.f) ? __fdividef(an[j][3], ad[j][3]) : 0.f;
            u32x2 xr = *(const u32x2*)&xbf32[(size_t)(n0 + j) * 32 + 2 * h16];
            u32x2 o;
            o.x = pack2(lo2f(xr.x) + a0, hi2f(xr.x) + a1);
            o.y = pack2(lo2f(xr.y) + a2, hi2f(xr.y) + a3);
            *(u32x2*)&h64bf32[(size_t)(n0 + j) * 32 + 2 * h16] = o;
        }
    }
}

// fused node MLP: 64->128 (acts direct from h64bf), LN (shfl), ReLU, 128->64
__global__ __launch_bounds__(256) void mlp_fused(const u16* __restrict__ h64bf,
        u16* __restrict__ xbf,
        const float* __restrict__ W, const short8* __restrict__ Wf, int r) {
    __shared__ u32 lds[4 * 1088];
    int wv = threadIdx.x >> 6, lane = threadIdx.x & 63;
    int q = lane >> 4, mr = lane & 15;
    u32* bufY = lds + wv * 1088;
    long nbase = (long)blockIdx.x * 64 + wv * 16;
    long row = nbase + mr;
    long rc = (row < N_NODES) ? row : (N_NODES - 1);
    short8 act[2];
#pragma unroll
    for (int kt = 0; kt < 2; kt++)
        act[kt] = *(const short8*)&h64bf[rc * 64 + kt * 32 + q * 8];
    f32x4 acc[8];
    mfma_layer_reg<2, 8>(act, lane, Wf, FR_MP0 + r * 16, W + MP_B0 + r * 128, acc);
    float s = 0.f, sq = 0.f;
#pragma unroll
    for (int nt = 0; nt < 8; nt++)
#pragma unroll
        for (int rr = 0; rr < 4; rr++) { float v = acc[nt][rr]; s += v; sq = fmaf(v, v, sq); }
    s += __shfl_xor(s, 16, 64);  s += __shfl_xor(s, 32, 64);
    sq += __shfl_xor(sq, 16, 64); sq += __shfl_xor(sq, 32, 64);
    float mu = s * (1.f / 128.f);
    float var = sq * (1.f / 128.f) - mu * mu;
    float inv = rsqrtf(var + 1e-5f);
    const float* LW = W + LNW_O + r * 128;
    const float* LB = W + LNB_O + r * 128;
#pragma unroll
    for (int nt = 0; nt < 8; nt++) {
        f32x4 lw = *(const f32x4*)(LW + nt * 16 + q * 4);
        f32x4 lb = *(const f32x4*)(LB + nt * 16 + q * 4);
        float u0 = fmaxf(fmaf((acc[nt][0] - mu) * inv, lw[0], lb[0]), 0.f);
        float u1 = fmaxf(fmaf((acc[nt][1] - mu) * inv, lw[1], lb[1]), 0.f);
        float u2 = fmaxf(fmaf((acc[nt][2] - mu) * inv, lw[2], lb[2]), 0.f);
        float u3 = fmaxf(fmaf((acc[nt][3] - mu) * inv, lw[3], lb[3]), 0.f);
        u32x2 pb; pb.x = pack2(u0, u1); pb.y = pack2(u2, u3);
        *(u32x2*)&bufY[mr * 68 + nt * 8 + q * 2] = pb;
    }
    WAVE_SYNC();
    f32x4 acc2[4];
    mfma_layer<4, 4, 68>(bufY, lane, Wf, FR_MP1 + r * 16, W + MP_B1 + r * 64, acc2);
    if (row < N_NODES) {
#pragma unroll
        for (int nt = 0; nt < 4; nt++) {
            f32x4 v = acc2[nt];
            u32x2 pb; pb.x = pack2(v[0], v[1]); pb.y = pack2(v[2], v[3]);
            *(u32x2*)&xbf[row * 64 + nt * 16 + q * 4] = pb;
        }
    }
}

__global__ __launch_bounds__(256) void policy_head(const void* nf,
        const u16* __restrict__ xbf, void* out, const float* __restrict__ W,
        const short8* __restrict__ Wf, const u32* __restrict__ gtbl) {
    __shared__ u32 lds[4 * 576];
    __shared__ u32 tbl[TANH_TBL_N];
    bool bf = detect_bf(nf);
    load_tbl(gtbl, tbl);
    int wv = threadIdx.x >> 6, lane = threadIdx.x & 63;
    int q = lane >> 4, mr = lane & 15;
    u32* bufY = lds + wv * 576;
    long nbase = (long)blockIdx.x * 64 + wv * 16;
    long row = nbase + mr;
    long rc = (row < N_NODES) ? row : (N_NODES - 1);
    short8 act[2];
#pragma unroll
    for (int kt = 0; kt < 2; kt++)
        act[kt] = *(const short8*)&xbf[rc * 64 + kt * 32 + q * 8];
    f32x4 acc[4];
    mfma_layer_reg<2, 4>(act, lane, Wf, FR_PI0, W + PI_B0, acc);
    tanh_pack_lds<4, 36>(acc, bufY, lane, tbl);
    WAVE_SYNC();
    mfma_layer<2, 4, 36>(bufY, lane, Wf, FR_PI1, W + PI_B1, acc);
    float o = 0.f;
#pragma unroll
    for (int nt = 0; nt < 4; nt++) {
        f32x4 w2 = *(const f32x4*)(W + PI_W2 + nt * 16 + q * 4);
#pragma unroll
        for (int rr = 0; rr < 4; rr++) o = fmaf(lut_tanh(tbl, acc[nt][rr]), w2[rr], o);
    }
    o += __shfl_xor(o, 16, 64);
    o += __shfl_xor(o, 32, 64);
    if (lane < 16 && row < N_NODES) {
        float means = 30.f * (o + W[PI_B2]);
        if (bf) ((u16*)out)[row] = f2b(means);
        else    ((float*)out)[row] = means;
    }
}

// ---------------- launch ----------------
extern "C" void kernel_launch(void* const* d_in, const int* in_sizes, int n_in,
                              void* d_out, int out_size, void* d_ws, size_t ws_size,
                              hipStream_t stream) {
    char* ws = (char*)d_ws;
    float* W      = (float*)(ws + OFF_W);
    u16*   Wb     = (u16*)(ws + OFF_WB);
    const short8* Wf = (const short8*)(ws + OFF_WB);
    u32*   gtbl   = (u32*)(ws + OFF_TBL);
    u16*   xb0    = (u16*)(ws + OFF_XB0);
    u16*   xb1    = (u16*)(ws + OFF_XB1);
    u16*   h64bf  = (u16*)(ws + OFF_H64B);
    u32*   h64b32 = (u32*)(ws + OFF_H64B);
    u32*   ebuf32 = (u32*)(ws + OFF_E);
    int*   pra    = (int*)(ws + OFF_PRA);
    int*   cnt16  = (int*)(ws + OFF_CNT16);
    int*   cntTot = (int*)(ws + OFF_CNTT);
    int*   perm   = (int*)(ws + OFF_PERM);
    int*   rank   = (int*)(ws + OFF_RANK);
    int*   srcs   = (int*)(ws + OFF_SRCS);
    int*   bsum   = (int*)(ws + OFF_BSUM);

    const void* nf  = d_in[0];
    const int* ei   = (const int*)d_in[2];
    const int* srcv = ei;
    const int* dstv = ei + N_EDGES;

    Ptrs24 ps;
    for (int k = 0; k < 24; k++) ps.p[k] = d_in[3 + k];
    prep_kernel<<<(PREP_TOTAL + 255) / 256, 256, 0, stream>>>(nf, ps, W, Wb, gtbl, cnt16);

    hist_kernel<<<(N_EDGES + 255) / 256, 256, 0, stream>>>(dstv, cnt16, rank);
    padfix_kernel<<<(N_NODES + 255) / 256, 256, 0, stream>>>(cnt16, cntTot);
    const int scanABlocks = (M_ITEMS + 1 + 2047) / 2048;   // 391
    scanA<<<scanABlocks, 1024, 0, stream>>>(cnt16, pra, bsum);
    scanB<<<1, 64, 0, stream>>>(bsum, scanABlocks);
    scanC<<<(M_ITEMS + 1024) / 1024, 1024, 0, stream>>>(bsum, cntTot, pra, srcs);
    scatter_kernel<<<(N_EDGES + 255) / 256, 256, 0, stream>>>(dstv, srcv, rank, pra, perm, srcs);

    node_encoder<<<(N_NODES + 63) / 64, 256, 0, stream>>>(nf, xb0, W, Wf, gtbl);
    edge_encoder<<<EDGE_SPLIT_BLOCKS, 256, 0, stream>>>(nf, d_in[1], ebuf32, perm, W, Wf, gtbl, 0);
    edge_encoder<<<EDGE_SPLIT_BLOCKS, 256, 0, stream>>>(nf, d_in[1], ebuf32, perm, W, Wf, gtbl, 1);

    u16* xbc = xb0; u16* xbn = xb1;
    const int aggHalfBlocks = AGG_HALF_WAVES / 4;   // 3125 blocks per half
    aggregate_kernel<0><<<aggHalfBlocks, 256, 0, stream>>>((const u32*)xbc, ebuf32, srcs, pra, h64b32, 0);
    aggregate_kernel<0><<<aggHalfBlocks, 256, 0, stream>>>((const u32*)xbc, ebuf32, srcs, pra, h64b32, 1);
    mlp_fused<<<(N_NODES + 63) / 64, 256, 0, stream>>>(h64bf, xbn, W, Wf, 0);
    { u16* tb = xbc; xbc = xbn; xbn = tb; }
    aggregate_kernel<1><<<aggHalfBlocks, 256, 0, stream>>>((const u32*)xbc, ebuf32, srcs, pra, h64b32, 0);
    aggregate_kernel<1><<<aggHalfBlocks, 256, 0, stream>>>((const u32*)xbc, ebuf32, srcs, pra, h64b32, 1);
    mlp_fused<<<(N_NODES + 63) / 64, 256, 0, stream>>>(h64bf, xbn, W, Wf, 1);
    { u16* tb = xbc; xbc = xbn; xbn = tb; }
    aggregate_kernel<2><<<aggHalfBlocks, 256, 0, stream>>>((const u32*)xbc, ebuf32, srcs, pra, h64b32, 0);
    aggregate_kernel<2><<<aggHalfBlocks, 256, 0, stream>>>((const u32*)xbc, ebuf32, srcs, pra, h64b32, 1);
    mlp_fused<<<(N_NODES + 63) / 64, 256, 0, stream>>>(h64bf, xbn, W, Wf, 2);
    { u16* tb = xbc; xbc = xbn; xbn = tb; }

    policy_head<<<(N_NODES + 63) / 64, 256, 0, stream>>>(nf, xbc, d_out, W, Wf, gtbl);
}